// Round 13
// baseline (3361.917 us; speedup 1.0000x reference)
//
#include <hip/hip_runtime.h>

#define S_ 50
#define B_ 64
#define T_ 32
#define E_ 512
#define H_ 1024
#define C_ 1024
#define V_ 32000
#define TS_ 31            // T-1 steps
#define NR_ 1984          // TS_*B_ rows
#define NBLK_ 192         // persistent-loop grid size (3 roles x 64)

typedef __attribute__((ext_vector_type(8))) short s8v;   // 8 x bf16 bits
typedef __attribute__((ext_vector_type(4))) float f4v;   // MFMA acc / float4
typedef unsigned long long u64;

static __device__ __forceinline__ float b2f(ushort u) {
  unsigned x = ((unsigned)u) << 16; float f; __builtin_memcpy(&f, &x, 4); return f;
}
static __device__ __forceinline__ ushort f2b(float f) {
  unsigned x; __builtin_memcpy(&x, &f, 4);
  x = x + 0x7FFFu + ((x >> 16) & 1u);
  return (ushort)(x >> 16);
}
static __device__ __forceinline__ float sigm(float x) { return 1.f / (1.f + __expf(-x)); }
static __device__ __forceinline__ float tanh_fast(float x) {
  float e = __expf(2.f * x);
  return 1.f - 2.f / (e + 1.f);
}

// ---- coherence-point I/O: producers publish via sc0 sc1; flags re-read uncached ----
static __device__ __forceinline__ s8v ld_sc16w(const void* p) {
  s8v v;
  asm volatile("global_load_dwordx4 %0, %1, off sc0 sc1\n\ts_waitcnt vmcnt(0)"
               : "=&v"(v) : "v"(p) : "memory");
  return v;
}
static __device__ __forceinline__ void st_sc8(void* p, u64 v) {
  asm volatile("global_store_dwordx2 %0, %1, off sc0 sc1" :: "v"(p), "v"(v) : "memory");
}
static __device__ __forceinline__ void st_scu16(ushort* p, unsigned v) {
  asm volatile("global_store_short %0, %1, off sc0 sc1" :: "v"(p), "v"(v) : "memory");
}

// A-frag: lane holds row (l&15), k = kb + 8*(l>>4) + j   (16B contiguous cached load)
static __device__ __forceinline__ s8v ldfrag(const ushort* base, int ld, int row0, int kb, int lane) {
  const ushort* p = base + (size_t)(row0 + (lane & 15)) * ld + (kb + ((lane >> 4) << 3));
  return *reinterpret_cast<const s8v*>(p);
}

// B-frag from swizzled LDS: row r (2KB rows), byte col = kb*2 + (l>>4)*16, XOR (r&7)<<4
static __device__ __forceinline__ s8v ldsfrag(const ushort* base, int r, int kb, int lane) {
  unsigned o = (unsigned)r * 2048u +
               (((unsigned)(kb * 2 + ((lane >> 4) << 4))) ^ ((unsigned)((r & 7) << 4)));
  return *reinterpret_cast<const s8v*>((const char*)base + o);
}

// ---------------- fused prologue: converts + transposes + gather (one dispatch) ----------------

struct CvtSeg { const float* s; ushort* d; unsigned n4; };
struct PrepP {
  CvtSeg seg[8];
  const float* Wc2h; ushort* wc2hT;   // wc2hT[c*1024+h] = Wc2h[h*1024+c]
  const float* Wh2c; ushort* wh2cT;   // wh2cT[k*1024+c] = Wh2c[c*1024+k]
  const int* y; const float* emb; ushort* xb;
  unsigned tot0, tot1, tot2, tot3;    // cumulative region ends
};

__global__ void k_prep(PrepP pp) {
  for (unsigned q = blockIdx.x * 256 + threadIdx.x; q < pp.tot3; q += gridDim.x * 256) {
    if (q < pp.tot0) {
      unsigned off = q;
      int s = 0;
      while (off >= pp.seg[s].n4) { off -= pp.seg[s].n4; s++; }
      float4 v = reinterpret_cast<const float4*>(pp.seg[s].s)[off];
      ushort4 o; o.x = f2b(v.x); o.y = f2b(v.y); o.z = f2b(v.z); o.w = f2b(v.w);
      reinterpret_cast<ushort4*>(pp.seg[s].d)[off] = o;
    } else if (q < pp.tot1) {
      unsigned g = q - pp.tot0;
      int h = g & 1023, c = g >> 10;
      pp.wc2hT[(size_t)c * 1024 + h] = f2b(pp.Wc2h[(size_t)h * 1024 + c]);
    } else if (q < pp.tot2) {
      unsigned g = q - pp.tot1;
      int c = g >> 10, k = g & 1023;
      pp.wh2cT[(size_t)k * 1024 + c] = f2b(pp.Wh2c[(size_t)c * 1024 + k]);
    } else {
      unsigned g = q - pp.tot2;
      int i = g >> 7;
      int c = (g & 127) << 2;
      int idx = pp.y[i];
      float4 v = make_float4(0.f, 0.f, 0.f, 0.f);
      if (idx != 0) v = *reinterpret_cast<const float4*>(pp.emb + (size_t)idx * E_ + c);
      ushort4 o; o.x = f2b(v.x); o.y = f2b(v.y); o.z = f2b(v.z); o.w = f2b(v.w);
      *reinterpret_cast<ushort4*>(pp.xb + (size_t)i * E_ + c) = o;
    }
  }
}

// ---------------- generic GEMM: out[m,n]=sum_k A[m,k]*B[n,k] (+bias)(opt tanh), 64x128 blocks ----
// kperm=1: write outB in K-permuted layout [b][gate][s][c] (m = s*64+b, n = g*1024+c)
__global__ void gemm_bt(const ushort* __restrict__ A, const ushort* __restrict__ Bm,
                        const float* __restrict__ bias, ushort* __restrict__ outB,
                        int M, int N, int K, int act, int kperm) {
  int l = threadIdx.x & 63, w = threadIdx.x >> 6;
  int m0 = blockIdx.y * 64 + w * 16;
  int n0 = blockIdx.x * 128;
  f4v acc[8] = {{0.f,0.f,0.f,0.f},{0.f,0.f,0.f,0.f},{0.f,0.f,0.f,0.f},{0.f,0.f,0.f,0.f},
                {0.f,0.f,0.f,0.f},{0.f,0.f,0.f,0.f},{0.f,0.f,0.f,0.f},{0.f,0.f,0.f,0.f}};
  for (int kb = 0; kb < K; kb += 32) {
    s8v a = ldfrag(A, K, m0, kb, l);
#pragma unroll
    for (int nt = 0; nt < 8; nt++) {
      s8v b = ldfrag(Bm, K, n0 + nt * 16, kb, l);
      acc[nt] = __builtin_amdgcn_mfma_f32_16x16x32_bf16(a, b, acc[nt], 0, 0, 0);
    }
  }
  int rb = (l >> 4) * 4;
  int col = l & 15;
#pragma unroll
  for (int nt = 0; nt < 8; nt++) {
    int n = n0 + nt * 16 + col;
    float bv = bias ? bias[n] : 0.f;
#pragma unroll
    for (int i = 0; i < 4; i++) {
      int m = m0 + rb + i;
      float v = acc[nt][i] + bv;
      if (act) v = tanhf(v);
      size_t o;
      if (kperm) {
        int bq = m & 63, sq = m >> 6, g = n >> 10, cc = n & 1023;
        o = (((size_t)bq * 3 + g) * 50 + sq) * 1024 + cc;
      } else {
        o = (size_t)m * N + n;
      }
      outB[o] = f2b(v);
    }
  }
}

// 3 independent GEMMs in one dispatch (gi0, ctxp, wcomb)
struct GJob { const ushort* A; const ushort* B; const float* bias; ushort* outB;
              int N, K, nbx; unsigned blk0; };
struct GMulti { GJob j[3]; };

__global__ void gemm_multi(GMulti g) {
  int blk = blockIdx.x;
  int jb = (blk >= g.j[2].blk0) ? 2 : ((blk >= g.j[1].blk0) ? 1 : 0);
  GJob job = g.j[jb];
  unsigned local = blk - job.blk0;
  int by = local / job.nbx, bx = local % job.nbx;
  int l = threadIdx.x & 63, w = threadIdx.x >> 6;
  int m0 = by * 64 + w * 16;
  int n0 = bx * 128;
  f4v acc[8] = {{0.f,0.f,0.f,0.f},{0.f,0.f,0.f,0.f},{0.f,0.f,0.f,0.f},{0.f,0.f,0.f,0.f},
                {0.f,0.f,0.f,0.f},{0.f,0.f,0.f,0.f},{0.f,0.f,0.f,0.f},{0.f,0.f,0.f,0.f}};
  for (int kb = 0; kb < job.K; kb += 32) {
    s8v a = ldfrag(job.A, job.K, m0, kb, l);
#pragma unroll
    for (int nt = 0; nt < 8; nt++) {
      s8v b = ldfrag(job.B, job.K, n0 + nt * 16, kb, l);
      acc[nt] = __builtin_amdgcn_mfma_f32_16x16x32_bf16(a, b, acc[nt], 0, 0, 0);
    }
  }
  int rb = (l >> 4) * 4;
  int col = l & 15;
#pragma unroll
  for (int nt = 0; nt < 8; nt++) {
    int n = n0 + nt * 16 + col;
    float bv = job.bias ? job.bias[n] : 0.f;
#pragma unroll
    for (int i = 0; i < 4; i++) {
      int m = m0 + rb + i;
      job.outB[(size_t)m * job.N + n] = f2b(acc[nt][i] + bv);
    }
  }
}

// ---------------- persistent sequential loop (2 hops/step) ----------------

struct LoopP {
  const ushort* whh0b; const ushort* gi0b; const ushort* whh1b;
  const ushort* Kp; const ushort* ctxpb; const ushort* wh2cT;
  const float* bhh0; const float* bih1; const float* bhh1; const float* wmlp;
  const ushort* h0b;
  ushort* h1b;   // TS x B x H   (per-step fresh buffers -> cached reads are safe)
  ushort* gh1b;  // TS x B x 3H
  ushort* H2b;   // TS x B x H
  ushort* flags; // 3 groups x 128-ushort stride (64 used); memset 0 per launch
};

#define FA 0
#define FG 1
#define FD 2
static __device__ __forceinline__ ushort* flg(ushort* base, int k) { return base + k * 128; }

// producer: drain sc-stores at coherence point, then u16-store step number
static __device__ __forceinline__ void arrive(ushort* slot, unsigned val) {
  asm volatile("s_waitcnt vmcnt(0)" ::: "memory");
  __syncthreads();
  if (threadIdx.x == 0) st_scu16(slot, val);
}
// consumer: 8 lanes x dwordx4 covers all 64 u16 flags
static __device__ __forceinline__ void waitflag(const ushort* slot64, unsigned tgt) {
  __syncthreads();
  if (threadIdx.x < 64) {
    const bool rd = threadIdx.x < 8;
    const ushort* myp = slot64 + threadIdx.x * 8;
    for (;;) {
      int ok = 1;
      if (rd) {
        s8v v = ld_sc16w(myp);
        unsigned mn = 0xFFFFu;
#pragma unroll
        for (int j = 0; j < 8; j++) mn = min(mn, (unsigned)(ushort)v[j]);
        ok = (mn >= tgt);
      }
      if (__all(ok)) break;
      __builtin_amdgcn_s_sleep(4);
    }
  }
  __syncthreads();
}

// roles: 0 (blk 0-63)=GRU0/Whh0 ; 1 (64-127)=fused h1row/hid-mv/attn/Ksum/GRU1 ; 2 (128-191)=gh1/Whh1
__global__ __launch_bounds__(256) void k_loop(LoopP p) {
  __shared__ __align__(16) ushort ldsW[48 * 1024];   // 96KB, 48 rows x 2KB, XOR-swizzled
  __shared__ __align__(16) float hs[C_];
  __shared__ float sc[S_];
  __shared__ float al[S_];
  __shared__ __align__(8) ushort stile[64 * 16];     // role0/1: epilogue tile / h1row
  __shared__ __align__(8) ushort stile3[64 * 48];    // gh1-role 3-gate re-layout

  const int tid = threadIdx.x;
  const int blk = blockIdx.x;
  const int l = tid & 63, w = tid >> 6;
  const int role = blk >> 6;
  const int sub = blk & 63;

  // ---- stage this block's weight slice into swizzled LDS (once; role 1 has none) ----
  if (role != 1) {
    const ushort* src = (role == 0) ? p.whh0b : p.whh1b;
    for (int idx = tid; idx < 48 * 128; idx += 256) {
      int r = idx >> 7, c = idx & 127;
      int grow;
      if (role == 0) grow = (r >> 4) * H_ + sub * 16 + (r & 15);
      else           grow = sub * 48 + r;
      s8v v = *reinterpret_cast<const s8v*>(src + (size_t)grow * 1024 + c * 8);
      unsigned o = (unsigned)r * 2048u + (((unsigned)(c * 16)) ^ ((unsigned)((r & 7) << 4)));
      *reinterpret_cast<s8v*>((char*)ldsW + o) = v;
    }
  }
  __syncthreads();

  const int rr = l & 15;
  const int m0 = w * 16;
  const int rb = (l >> 4) * 4, c15 = l & 15;

  for (int t = 0; t < TS_; t++) {
    ushort* h1t  = p.h1b  + (size_t)t * B_ * H_;
    ushort* gh1t = p.gh1b + (size_t)t * B_ * 3 * H_;
    ushort* h2t  = p.H2b  + (size_t)t * B_ * H_;

    if (role == 0) {
      // ---- phase A: h1 = GRU0(h_prev) ----
      if (t) waitflag(flg(p.flags, FD), (unsigned)t);
      const ushort* hpb = t ? (p.H2b + (size_t)(t - 1) * B_ * H_) : p.h0b;
      const ushort* gi0t = p.gi0b + (size_t)t * B_ * 3 * H_;
      int c = sub * 16 + c15;
      f4v aR = {0.f,0.f,0.f,0.f}, aZ = {0.f,0.f,0.f,0.f}, aN = {0.f,0.f,0.f,0.f};
#pragma unroll 4
      for (int kb = 0; kb < H_; kb += 32) {
        s8v a = ldfrag(hpb, H_, m0, kb, l);
        aR = __builtin_amdgcn_mfma_f32_16x16x32_bf16(a, ldsfrag(ldsW, rr, kb, l), aR, 0, 0, 0);
        aZ = __builtin_amdgcn_mfma_f32_16x16x32_bf16(a, ldsfrag(ldsW, 16 + rr, kb, l), aZ, 0, 0, 0);
        aN = __builtin_amdgcn_mfma_f32_16x16x32_bf16(a, ldsfrag(ldsW, 32 + rr, kb, l), aN, 0, 0, 0);
      }
#pragma unroll
      for (int i = 0; i < 4; i++) {
        int m = m0 + rb + i;
        const ushort* gi = gi0t + (size_t)m * (3 * H_);
        float gir = b2f(gi[c]), giz = b2f(gi[H_ + c]), gin = b2f(gi[2 * H_ + c]);
        float ghr = aR[i] + p.bhh0[c], ghz = aZ[i] + p.bhh0[H_ + c], ghn = aN[i] + p.bhh0[2 * H_ + c];
        float r = sigm(gir + ghr);
        float zg = sigm(giz + ghz);
        float nn = tanh_fast(gin + r * ghn);
        float h1 = (1.f - zg) * nn + zg * b2f(hpb[(size_t)m * H_ + c]);
        stile[m * 16 + c15] = f2b(h1);
      }
      __syncthreads();
      {
        int row = tid >> 2, ch = tid & 3;
        u64 v = *reinterpret_cast<u64*>(&stile[row * 16 + ch * 4]);
        st_sc8(&h1t[(size_t)row * H_ + sub * 16 + ch * 4], v);
      }
      arrive(flg(p.flags, FA) + sub, (unsigned)(t + 1));

    } else if (role == 1) {
      // ---- fused: h1-row stage + hid m-v + attention + Ksum + GRU1 epilogue (b = sub) ----
      waitflag(flg(p.flags, FA), (unsigned)(t + 1));
      int b = sub;
      // stage h1[b,:] into LDS (bf16): 256 x 8B cached reads of a fresh buffer
      {
        u64 hv = *reinterpret_cast<const u64*>(h1t + (size_t)b * H_ + tid * 4);
        *reinterpret_cast<u64*>(&stile[tid * 4]) = hv;
      }
      __syncthreads();
      // hid[b, c0..c0+3] = sum_k h1[k] * Wh2c[c,k]  via wh2cT[k][c] (coalesced)
      {
        int c0 = tid * 4;
        float a0 = 0.f, a1 = 0.f, a2 = 0.f, a3 = 0.f;
#pragma unroll 2
        for (int kb = 0; kb < H_; kb += 8) {
          s8v h8 = *reinterpret_cast<const s8v*>(&stile[kb]);   // LDS broadcast
#pragma unroll
          for (int j = 0; j < 8; j++) {
            ushort4 wv = *reinterpret_cast<const ushort4*>(p.wh2cT + (size_t)(kb + j) * 1024 + c0);
            float hk = b2f((ushort)h8[j]);
            a0 += hk * b2f(wv.x); a1 += hk * b2f(wv.y);
            a2 += hk * b2f(wv.z); a3 += hk * b2f(wv.w);
          }
        }
        hs[c0] = a0; hs[c0 + 1] = a1; hs[c0 + 2] = a2; hs[c0 + 3] = a3;
      }
      __syncthreads();
      // attention scores + softmax
      for (int s = w; s < S_; s += 4) {
        const ushort* row = p.ctxpb + ((size_t)s * B_ + b) * C_;
        float a = 0.f;
        for (int c4 = l * 4; c4 < C_; c4 += 256) {
          ushort4 cv = *reinterpret_cast<const ushort4*>(row + c4);
          f4v hv4 = *reinterpret_cast<const f4v*>(&hs[c4]);
          float4 wv = *reinterpret_cast<const float4*>(p.wmlp + c4);
          a += tanh_fast(b2f(cv.x) + hv4[0]) * wv.x;
          a += tanh_fast(b2f(cv.y) + hv4[1]) * wv.y;
          a += tanh_fast(b2f(cv.z) + hv4[2]) * wv.z;
          a += tanh_fast(b2f(cv.w) + hv4[3]) * wv.w;
        }
        for (int m = 32; m; m >>= 1) a += __shfl_xor(a, m, 64);
        if (l == 0) sc[s] = a;
      }
      __syncthreads();
      {
        float mx = -1e30f;
        for (int s = 0; s < S_; s++) mx = fmaxf(mx, sc[s]);
        float sm = 0.f;
        for (int s = 0; s < S_; s++) sm += __expf(sc[s] - mx);
        if (tid < S_) al[tid] = __expf(sc[tid] - mx) / sm;
      }
      __syncthreads();
      {
        int c0 = tid * 4;
        // gi1 = sum_s al[s] * K[b,g,s,:] — only needs al + prologue Kp => BEFORE the FG wait
        const ushort* kb0 = p.Kp + (size_t)b * 153600 + c0;   // 3*50*1024 per b
        float rc0=0.f,rc1=0.f,rc2=0.f,rc3=0.f, zc0=0.f,zc1=0.f,zc2=0.f,zc3=0.f,
              nc0=0.f,nc1=0.f,nc2=0.f,nc3=0.f;
#pragma unroll 2
        for (int s = 0; s < S_; s++) {
          float a = al[s];
          ushort4 kr = *reinterpret_cast<const ushort4*>(kb0 + s * 1024);
          ushort4 kz = *reinterpret_cast<const ushort4*>(kb0 + 51200 + s * 1024);
          ushort4 kn = *reinterpret_cast<const ushort4*>(kb0 + 102400 + s * 1024);
          rc0 += a * b2f(kr.x); rc1 += a * b2f(kr.y); rc2 += a * b2f(kr.z); rc3 += a * b2f(kr.w);
          zc0 += a * b2f(kz.x); zc1 += a * b2f(kz.y); zc2 += a * b2f(kz.z); zc3 += a * b2f(kz.w);
          nc0 += a * b2f(kn.x); nc1 += a * b2f(kn.y); nc2 += a * b2f(kn.z); nc3 += a * b2f(kn.w);
        }

        waitflag(flg(p.flags, FG), (unsigned)(t + 1));   // gh1 ready (overlapped by K-sum)

        u64 ghr8 = *reinterpret_cast<const u64*>(&gh1t[(size_t)b * 3072 + c0]);
        u64 ghz8 = *reinterpret_cast<const u64*>(&gh1t[(size_t)b * 3072 + 1024 + c0]);
        u64 ghn8 = *reinterpret_cast<const u64*>(&gh1t[(size_t)b * 3072 + 2048 + c0]);
        u64 h18  = *reinterpret_cast<const u64*>(&stile[c0]);   // h1 row from LDS
        float rcv[4] = {rc0, rc1, rc2, rc3};
        float zcv[4] = {zc0, zc1, zc2, zc3};
        float ncv[4] = {nc0, nc1, nc2, nc3};
        u64 outp = 0;
#pragma unroll
        for (int j = 0; j < 4; j++) {
          int c = c0 + j;
          float gir = rcv[j] + p.bih1[c];
          float giz = zcv[j] + p.bih1[H_ + c];
          float gin = ncv[j] + p.bih1[2 * H_ + c];
          float ghr = b2f((ushort)(ghr8 >> (16 * j))) + p.bhh1[c];
          float ghz = b2f((ushort)(ghz8 >> (16 * j))) + p.bhh1[H_ + c];
          float ghn = b2f((ushort)(ghn8 >> (16 * j))) + p.bhh1[2 * H_ + c];
          float r = sigm(gir + ghr);
          float zg = sigm(giz + ghz);
          float nn = tanh_fast(gin + r * ghn);
          float h1v = b2f((ushort)(h18 >> (16 * j)));
          float h2 = (1.f - zg) * nn + zg * h1v;
          outp |= (u64)f2b(h2) << (16 * j);
        }
        st_sc8(&h2t[(size_t)b * 1024 + c0], outp);
      }
      arrive(flg(p.flags, FD) + sub, (unsigned)(t + 1));

    } else {
      // ---- gh1 = h1 @ Whh1.T (48-col slice) -> bf16 ----
      waitflag(flg(p.flags, FA), (unsigned)(t + 1));
      {
        f4v aR = {0.f,0.f,0.f,0.f}, aZ = {0.f,0.f,0.f,0.f}, aN = {0.f,0.f,0.f,0.f};
#pragma unroll 4
        for (int kb = 0; kb < H_; kb += 32) {
          s8v a = ldfrag(h1t, H_, m0, kb, l);
          aR = __builtin_amdgcn_mfma_f32_16x16x32_bf16(a, ldsfrag(ldsW, rr, kb, l), aR, 0, 0, 0);
          aZ = __builtin_amdgcn_mfma_f32_16x16x32_bf16(a, ldsfrag(ldsW, 16 + rr, kb, l), aZ, 0, 0, 0);
          aN = __builtin_amdgcn_mfma_f32_16x16x32_bf16(a, ldsfrag(ldsW, 32 + rr, kb, l), aN, 0, 0, 0);
        }
#pragma unroll
        for (int i = 0; i < 4; i++) {
          int m = m0 + rb + i;
          stile3[m * 48 + c15]      = f2b(aR[i]);
          stile3[m * 48 + 16 + c15] = f2b(aZ[i]);
          stile3[m * 48 + 32 + c15] = f2b(aN[i]);
        }
        __syncthreads();
#pragma unroll
        for (int j = 0; j < 3; j++) {
          int idx = tid + 256 * j;
          int row = idx / 12, k = idx % 12, lc4 = k * 4;
          u64 v = *reinterpret_cast<u64*>(&stile3[row * 48 + lc4]);
          st_sc8(&gh1t[(size_t)row * (3 * H_) + (lc4 >> 4) * H_ + sub * 16 + (lc4 & 15)], v);
        }
      }
      arrive(flg(p.flags, FG) + sub, (unsigned)(t + 1));
    }
  }
}

// ---------------- epilogue: streaming LSE over vocab ----------------
#define LSE_NCH 40
#define LSE_TILES 50    // 16-col tiles per chunk (40*50*16 = 32000)

__global__ __launch_bounds__(512) void k_lse2(const ushort* __restrict__ logitb,
                                              const ushort* __restrict__ wopb,
                                              const float* __restrict__ bop,
                                              float* __restrict__ part) {
  __shared__ ushort Bs[2][16 * E_];   // 2 x 16KB (16 rows x 1024B)
  int tid = threadIdx.x, l = tid & 63, w = tid >> 6;
  int r0 = blockIdx.y * 128 + w * 16;
  int c0 = blockIdx.x * (LSE_TILES * 16);
  int arow = r0 + (l & 15);
  bool aok = arow < NR_;

  s8v afr[16];
#pragma unroll
  for (int kk = 0; kk < 16; kk++) {
    s8v z = {0,0,0,0,0,0,0,0};
    afr[kk] = aok ? *reinterpret_cast<const s8v*>(logitb + (size_t)arow * E_ + kk * 32 + ((l >> 4) << 3)) : z;
  }

  const int srow = tid >> 5;
  const int scb = (tid & 31) * 32;
  const unsigned sxr = (unsigned)((srow & 7) << 4);
  char* sdst0 = (char*)&Bs[0][0] + srow * 1024;
  char* sdst1 = (char*)&Bs[1][0] + srow * 1024;

  const int brow = l & 15;
  const unsigned lanep = (unsigned)((l >> 4) << 4);
  const unsigned xorv = (unsigned)((brow & 7) << 4);
  const char* bbase0 = (const char*)&Bs[0][0] + brow * 1024;
  const char* bbase1 = (const char*)&Bs[1][0] + brow * 1024;

  f4v mr = {-1e30f, -1e30f, -1e30f, -1e30f};
  f4v sr = {0.f, 0.f, 0.f, 0.f};

  {
    const char* src = (const char*)(wopb + (size_t)(c0 + srow) * E_) + scb;
    s8v g0 = *reinterpret_cast<const s8v*>(src);
    s8v g1 = *reinterpret_cast<const s8v*>(src + 16);
    *reinterpret_cast<s8v*>(sdst0 + ((unsigned)scb ^ sxr)) = g0;
    *reinterpret_cast<s8v*>(sdst0 + (((unsigned)scb + 16u) ^ sxr)) = g1;
  }
  __syncthreads();

  for (int tt = 0; tt < LSE_TILES; tt++) {
    int cur = tt & 1;
    bool more = (tt + 1) < LSE_TILES;
    s8v g0, g1;
    if (more) {
      const char* src = (const char*)(wopb + (size_t)(c0 + (tt + 1) * 16 + srow) * E_) + scb;
      g0 = *reinterpret_cast<const s8v*>(src);
      g1 = *reinterpret_cast<const s8v*>(src + 16);
    }
    const char* bbase = cur ? bbase1 : bbase0;
    f4v acc = {0.f, 0.f, 0.f, 0.f};
#pragma unroll
    for (int kk = 0; kk < 16; kk++) {
      unsigned off = ((unsigned)(kk * 64) + lanep) ^ xorv;
      s8v b = *reinterpret_cast<const s8v*>(bbase + off);
      acc = __builtin_amdgcn_mfma_f32_16x16x32_bf16(afr[kk], b, acc, 0, 0, 0);
    }
    float bv = bop[c0 + tt * 16 + (l & 15)];
#pragma unroll
    for (int i = 0; i < 4; i++) {
      float v = acc[i] + bv;
      if (v <= mr[i]) {
        sr[i] += __expf(v - mr[i]);
      } else {
        sr[i] = sr[i] * __expf(mr[i] - v) + 1.f;
        mr[i] = v;
      }
    }
    if (more) {
      char* sdst = cur ? sdst0 : sdst1;
      *reinterpret_cast<s8v*>(sdst + ((unsigned)scb ^ sxr)) = g0;
      *reinterpret_cast<s8v*>(sdst + (((unsigned)scb + 16u) ^ sxr)) = g1;
      __syncthreads();
    }
  }

  for (int sh = 1; sh < 16; sh <<= 1) {
#pragma unroll
    for (int i = 0; i < 4; i++) {
      float om = __shfl_xor(mr[i], sh, 64);
      float os = __shfl_xor(sr[i], sh, 64);
      float mn = fmaxf(mr[i], om);
      sr[i] = sr[i] * __expf(mr[i] - mn) + os * __expf(om - mn);
      mr[i] = mn;
    }
  }
  if ((l & 15) == 0) {
#pragma unroll
    for (int i = 0; i < 4; i++) {
      int row = r0 + (l >> 4) * 4 + i;
      if (row < NR_) {
        size_t o = ((size_t)row * LSE_NCH + blockIdx.x) * 2;
        part[o] = mr[i];
        part[o + 1] = sr[i];
      }
    }
  }
}

__global__ void k_final(const float* __restrict__ part, const ushort* __restrict__ logitb,
                        const float* __restrict__ Wop, const float* __restrict__ bop,
                        const int* __restrict__ y, float* __restrict__ nll) {
  int i = blockIdx.x * 256 + threadIdx.x;
  if (i >= NR_) return;
  float m = -1e30f;
  for (int c = 0; c < LSE_NCH; c++) m = fmaxf(m, part[((size_t)i * LSE_NCH + c) * 2]);
  float s = 0.f;
  for (int c = 0; c < LSE_NCH; c++) {
    size_t o = ((size_t)i * LSE_NCH + c) * 2;
    s += part[o + 1] * __expf(part[o] - m);
  }
  float lse = m + logf(s);
  int tgt = y[i + B_];
  float v = 0.f;
  if (tgt != 0) {
    const ushort* lr = logitb + (size_t)i * E_;
    const float* wr = Wop + (size_t)tgt * E_;
    float dot = 0.f;
    for (int k = 0; k < E_; k += 4) {
      ushort4 lv = *reinterpret_cast<const ushort4*>(lr + k);
      float4 wv = *reinterpret_cast<const float4*>(wr + k);
      dot += b2f(lv.x) * wv.x + b2f(lv.y) * wv.y + b2f(lv.z) * wv.z + b2f(lv.w) * wv.w;
    }
    dot += bop[tgt];
    v = lse - dot;
  }
  nll[i] = v;
}

__global__ void k_reduce(const float* __restrict__ nll, float* __restrict__ out) {
  __shared__ float sh[256];
  float a = 0.f;
  for (int i = threadIdx.x; i < NR_; i += 256) a += nll[i];
  sh[threadIdx.x] = a;
  __syncthreads();
  for (int s = 128; s; s >>= 1) {
    if (threadIdx.x < s) sh[threadIdx.x] += sh[threadIdx.x + s];
    __syncthreads();
  }
  if (threadIdx.x == 0) out[0] = sh[0];
}

// ---------------- host ----------------

extern "C" void kernel_launch(void* const* d_in, const int* in_sizes, int n_in,
                              void* d_out, int out_size, void* d_ws, size_t ws_size,
                              hipStream_t stream) {
  const float* ctx  = (const float*)d_in[0];
  const int*   y    = (const int*)d_in[1];
  const float* emb  = (const float*)d_in[2];
  const float* Wih0 = (const float*)d_in[3];
  const float* Whh0 = (const float*)d_in[4];
  const float* bih0 = (const float*)d_in[5];
  const float* bhh0 = (const float*)d_in[6];
  const float* Wih1 = (const float*)d_in[7];
  const float* Whh1 = (const float*)d_in[8];
  const float* bih1 = (const float*)d_in[9];
  const float* bhh1 = (const float*)d_in[10];
  const float* Wc2c = (const float*)d_in[11];
  const float* Wh2c = (const float*)d_in[12];
  const float* wmlp = (const float*)d_in[13];
  const float* Wc2h = (const float*)d_in[14];
  const float* Who  = (const float*)d_in[15];
  const float* bho  = (const float*)d_in[16];
  const float* Wop  = (const float*)d_in[17];
  const float* bop  = (const float*)d_in[18];

  char* ws = (char*)d_ws;
  size_t off = 0;
  auto alloc = [&](size_t bytes) { void* p = ws + off; off += (bytes + 4095) & ~size_t(4095); return p; };

  ushort* ctxb   = (ushort*)alloc((size_t)S_ * B_ * C_ * 2);
  ushort* wih0b  = (ushort*)alloc((size_t)3 * H_ * E_ * 2);
  ushort* whh0b  = (ushort*)alloc((size_t)3 * H_ * H_ * 2);
  ushort* wc2hT  = (ushort*)alloc((size_t)C_ * H_ * 2);
  ushort* wh2cT  = (ushort*)alloc((size_t)H_ * C_ * 2);
  ushort* wih1b  = (ushort*)alloc((size_t)3 * H_ * H_ * 2);
  ushort* whh1b  = (ushort*)alloc((size_t)3 * H_ * H_ * 2);
  ushort* whob   = (ushort*)alloc((size_t)E_ * H_ * 2);
  ushort* wopb   = (ushort*)alloc((size_t)V_ * E_ * 2);
  ushort* wc2cb  = (ushort*)alloc((size_t)C_ * C_ * 2);
  ushort* wcombb = (ushort*)alloc((size_t)3 * H_ * C_ * 2);
  ushort* Kp     = (ushort*)alloc((size_t)S_ * B_ * 3 * H_ * 2);
  ushort* xb     = (ushort*)alloc((size_t)NR_ * E_ * 2);
  ushort* gi0b   = (ushort*)alloc((size_t)NR_ * 3 * H_ * 2);
  ushort* ctxpb  = (ushort*)alloc((size_t)S_ * B_ * C_ * 2);
  ushort* H2b    = (ushort*)alloc((size_t)TS_ * B_ * H_ * 2);
  ushort* h0b    = (ushort*)alloc((size_t)B_ * H_ * 2);
  ushort* h1b    = (ushort*)alloc((size_t)TS_ * B_ * H_ * 2);
  ushort* gh1b   = (ushort*)alloc((size_t)TS_ * B_ * 3 * H_ * 2);
  ushort* logitb = (ushort*)alloc((size_t)NR_ * E_ * 2);
  float*  part   = (float*)alloc((size_t)2048 * LSE_NCH * 2 * 4);
  float*  nllb   = (float*)alloc((size_t)2048 * 4);
  ushort* flags  = (ushort*)alloc(3 * 128 * 2);
  (void)ws_size; (void)in_sizes; (void)n_in; (void)out_size;

  (void)hipMemsetAsync(h0b, 0, (size_t)B_ * H_ * 2, stream);
  (void)hipMemsetAsync(flags, 0, 3 * 128 * 2, stream);

  // fused prologue: 8 converts + 2 transposes + gather
  PrepP pp;
  auto seg = [&](int i, const float* s, ushort* d, size_t n) {
    pp.seg[i].s = s; pp.seg[i].d = d; pp.seg[i].n4 = (unsigned)(n / 4);
  };
  seg(0, ctx, ctxb, (size_t)S_ * B_ * C_);
  seg(1, Wih0, wih0b, (size_t)3 * H_ * E_);
  seg(2, Whh0, whh0b, (size_t)3 * H_ * H_);
  seg(3, Wih1, wih1b, (size_t)3 * H_ * H_);
  seg(4, Whh1, whh1b, (size_t)3 * H_ * H_);
  seg(5, Who, whob, (size_t)E_ * H_);
  seg(6, Wop, wopb, (size_t)V_ * E_);
  seg(7, Wc2c, wc2cb, (size_t)C_ * C_);
  unsigned t0 = 0;
  for (int i = 0; i < 8; i++) t0 += pp.seg[i].n4;
  pp.tot0 = t0;
  pp.tot1 = t0 + (unsigned)(H_ * C_);
  pp.tot2 = pp.tot1 + (unsigned)(C_ * H_);
  pp.tot3 = pp.tot2 + (unsigned)(NR_ * (E_ / 4));
  pp.Wc2h = Wc2h; pp.wc2hT = wc2hT;
  pp.Wh2c = Wh2c; pp.wh2cT = wh2cT;
  pp.y = y; pp.emb = emb; pp.xb = xb;
  k_prep<<<dim3(2048), 256, 0, stream>>>(pp);

  // 3 independent GEMMs in one dispatch: gi0, ctxp, wcomb
  GMulti gm;
  gm.j[0] = { xb,    wih0b, bih0,    gi0b,   3 * H_, E_, (3 * H_) / 128, 0 };
  gm.j[1] = { ctxb,  wc2cb, nullptr, ctxpb,  C_,     C_, C_ / 128,       (unsigned)((3 * H_ / 128) * (NR_ / 64)) };
  gm.j[2] = { wih1b, wc2hT, nullptr, wcombb, C_,     H_, C_ / 128,       gm.j[1].blk0 + (unsigned)((C_ / 128) * (S_ * B_ / 64)) };
  unsigned gtot = gm.j[2].blk0 + (unsigned)((C_ / 128) * (3 * H_ / 64));
  gemm_multi<<<dim3(gtot), 256, 0, stream>>>(gm);

  // K = ctx @ W_comb.T, written in [b][gate][s][c] layout (kperm=1)
  gemm_bt<<<dim3(3 * H_ / 128, S_ * B_ / 64), 256, 0, stream>>>(ctxb, wcombb, nullptr, Kp,
                                                                S_ * B_, 3 * H_, C_, 0, 1);

  LoopP p;
  p.whh0b = whh0b; p.gi0b = gi0b; p.whh1b = whh1b;
  p.Kp = Kp; p.ctxpb = ctxpb; p.wh2cT = wh2cT;
  p.bhh0 = bhh0; p.bih1 = bih1; p.bhh1 = bhh1; p.wmlp = wmlp;
  p.h0b = h0b;
  p.h1b = h1b; p.gh1b = gh1b;
  p.H2b = H2b; p.flags = flags;
  void* args[] = { (void*)&p };
  (void)hipLaunchCooperativeKernel(k_loop, dim3(NBLK_), dim3(256), args, 0, stream);

  gemm_bt<<<dim3(E_ / 128, NR_ / 64), 256, 0, stream>>>(H2b, whob, bho, logitb,
                                                        NR_, E_, H_, 1, 0);
  k_lse2<<<dim3(LSE_NCH, 16), 512, 0, stream>>>(logitb, wopb, bop, part);
  k_final<<<dim3(8), 256, 0, stream>>>(part, logitb, Wop, bop, y, nllb);
  k_reduce<<<dim3(1), 256, 0, stream>>>(nllb, (float*)d_out);
}

// Round 14
// 2200.276 us; speedup vs baseline: 1.5280x; 1.5280x over previous
//
#include <hip/hip_runtime.h>

#define S_ 50
#define B_ 64
#define T_ 32
#define E_ 512
#define H_ 1024
#define C_ 1024
#define V_ 32000
#define TS_ 31            // T-1 steps
#define NR_ 1984          // TS_*B_ rows
#define NBLK_ 192         // persistent-loop grid size (3 roles x 64)

typedef __attribute__((ext_vector_type(8))) short s8v;   // 8 x bf16 bits
typedef __attribute__((ext_vector_type(4))) float f4v;   // MFMA acc / float4
typedef unsigned long long u64;

static __device__ __forceinline__ float b2f(ushort u) {
  unsigned x = ((unsigned)u) << 16; float f; __builtin_memcpy(&f, &x, 4); return f;
}
static __device__ __forceinline__ ushort f2b(float f) {
  unsigned x; __builtin_memcpy(&x, &f, 4);
  x = x + 0x7FFFu + ((x >> 16) & 1u);
  return (ushort)(x >> 16);
}
static __device__ __forceinline__ float sigm(float x) { return 1.f / (1.f + __expf(-x)); }
static __device__ __forceinline__ float tanh_fast(float x) {
  float e = __expf(2.f * x);
  return 1.f - 2.f / (e + 1.f);
}

// ---- coherence-point I/O: producers publish via sc0 sc1; flags re-read uncached ----
static __device__ __forceinline__ s8v ld_sc16w(const void* p) {
  s8v v;
  asm volatile("global_load_dwordx4 %0, %1, off sc0 sc1\n\ts_waitcnt vmcnt(0)"
               : "=&v"(v) : "v"(p) : "memory");
  return v;
}
static __device__ __forceinline__ void st_sc8(void* p, u64 v) {
  asm volatile("global_store_dwordx2 %0, %1, off sc0 sc1" :: "v"(p), "v"(v) : "memory");
}
static __device__ __forceinline__ void st_scu16(ushort* p, unsigned v) {
  asm volatile("global_store_short %0, %1, off sc0 sc1" :: "v"(p), "v"(v) : "memory");
}

// A-frag: lane holds row (l&15), k = kb + 8*(l>>4) + j   (16B contiguous cached load)
static __device__ __forceinline__ s8v ldfrag(const ushort* base, int ld, int row0, int kb, int lane) {
  const ushort* p = base + (size_t)(row0 + (lane & 15)) * ld + (kb + ((lane >> 4) << 3));
  return *reinterpret_cast<const s8v*>(p);
}

// B-frag from swizzled LDS: row r (2KB rows), byte col = kb*2 + (l>>4)*16, XOR (r&7)<<4
static __device__ __forceinline__ s8v ldsfrag(const ushort* base, int r, int kb, int lane) {
  unsigned o = (unsigned)r * 2048u +
               (((unsigned)(kb * 2 + ((lane >> 4) << 4))) ^ ((unsigned)((r & 7) << 4)));
  return *reinterpret_cast<const s8v*>((const char*)base + o);
}

// ---------------- fused prologue: converts + transpose + gather (one dispatch) ----------------

struct CvtSeg { const float* s; ushort* d; unsigned n4; };
struct PrepP {
  CvtSeg seg[9];
  const float* Wc2h; ushort* wc2hT;   // wc2hT[c*1024+h] = Wc2h[h*1024+c]
  const int* y; const float* emb; ushort* xb;
  unsigned tot0, tot1, tot2;          // cumulative region ends
};

__global__ void k_prep(PrepP pp) {
  for (unsigned q = blockIdx.x * 256 + threadIdx.x; q < pp.tot2; q += gridDim.x * 256) {
    if (q < pp.tot0) {
      unsigned off = q;
      int s = 0;
      while (off >= pp.seg[s].n4) { off -= pp.seg[s].n4; s++; }
      float4 v = reinterpret_cast<const float4*>(pp.seg[s].s)[off];
      ushort4 o; o.x = f2b(v.x); o.y = f2b(v.y); o.z = f2b(v.z); o.w = f2b(v.w);
      reinterpret_cast<ushort4*>(pp.seg[s].d)[off] = o;
    } else if (q < pp.tot1) {
      unsigned g = q - pp.tot0;
      int h = g & 1023, c = g >> 10;
      pp.wc2hT[(size_t)c * 1024 + h] = f2b(pp.Wc2h[(size_t)h * 1024 + c]);
    } else {
      unsigned g = q - pp.tot1;
      int i = g >> 7;
      int c = (g & 127) << 2;
      int idx = pp.y[i];
      float4 v = make_float4(0.f, 0.f, 0.f, 0.f);
      if (idx != 0) v = *reinterpret_cast<const float4*>(pp.emb + (size_t)idx * E_ + c);
      ushort4 o; o.x = f2b(v.x); o.y = f2b(v.y); o.z = f2b(v.z); o.w = f2b(v.w);
      *reinterpret_cast<ushort4*>(pp.xb + (size_t)i * E_ + c) = o;
    }
  }
}

// ---------------- generic GEMM: out[m,n]=sum_k A[m,k]*B[n,k] (+bias)(opt tanh), 64x128 blocks ----
// kperm=1: write outB in K-permuted layout [b][gate][s][c] (m = s*64+b, n = g*1024+c)
__global__ void gemm_bt(const ushort* __restrict__ A, const ushort* __restrict__ Bm,
                        const float* __restrict__ bias, ushort* __restrict__ outB,
                        int M, int N, int K, int act, int kperm) {
  int l = threadIdx.x & 63, w = threadIdx.x >> 6;
  int m0 = blockIdx.y * 64 + w * 16;
  int n0 = blockIdx.x * 128;
  f4v acc[8] = {{0.f,0.f,0.f,0.f},{0.f,0.f,0.f,0.f},{0.f,0.f,0.f,0.f},{0.f,0.f,0.f,0.f},
                {0.f,0.f,0.f,0.f},{0.f,0.f,0.f,0.f},{0.f,0.f,0.f,0.f},{0.f,0.f,0.f,0.f}};
  for (int kb = 0; kb < K; kb += 32) {
    s8v a = ldfrag(A, K, m0, kb, l);
#pragma unroll
    for (int nt = 0; nt < 8; nt++) {
      s8v b = ldfrag(Bm, K, n0 + nt * 16, kb, l);
      acc[nt] = __builtin_amdgcn_mfma_f32_16x16x32_bf16(a, b, acc[nt], 0, 0, 0);
    }
  }
  int rb = (l >> 4) * 4;
  int col = l & 15;
#pragma unroll
  for (int nt = 0; nt < 8; nt++) {
    int n = n0 + nt * 16 + col;
    float bv = bias ? bias[n] : 0.f;
#pragma unroll
    for (int i = 0; i < 4; i++) {
      int m = m0 + rb + i;
      float v = acc[nt][i] + bv;
      if (act) v = tanhf(v);
      size_t o;
      if (kperm) {
        int bq = m & 63, sq = m >> 6, g = n >> 10, cc = n & 1023;
        o = (((size_t)bq * 3 + g) * 50 + sq) * 1024 + cc;
      } else {
        o = (size_t)m * N + n;
      }
      outB[o] = f2b(v);
    }
  }
}

// 3 independent GEMMs in one dispatch (gi0, ctxp, wcomb)
struct GJob { const ushort* A; const ushort* B; const float* bias; ushort* outB;
              int N, K, nbx; unsigned blk0; };
struct GMulti { GJob j[3]; };

__global__ void gemm_multi(GMulti g) {
  int blk = blockIdx.x;
  int jb = (blk >= (int)g.j[2].blk0) ? 2 : ((blk >= (int)g.j[1].blk0) ? 1 : 0);
  GJob job = g.j[jb];
  unsigned local = blk - job.blk0;
  int by = local / job.nbx, bx = local % job.nbx;
  int l = threadIdx.x & 63, w = threadIdx.x >> 6;
  int m0 = by * 64 + w * 16;
  int n0 = bx * 128;
  f4v acc[8] = {{0.f,0.f,0.f,0.f},{0.f,0.f,0.f,0.f},{0.f,0.f,0.f,0.f},{0.f,0.f,0.f,0.f},
                {0.f,0.f,0.f,0.f},{0.f,0.f,0.f,0.f},{0.f,0.f,0.f,0.f},{0.f,0.f,0.f,0.f}};
  for (int kb = 0; kb < job.K; kb += 32) {
    s8v a = ldfrag(job.A, job.K, m0, kb, l);
#pragma unroll
    for (int nt = 0; nt < 8; nt++) {
      s8v b = ldfrag(job.B, job.K, n0 + nt * 16, kb, l);
      acc[nt] = __builtin_amdgcn_mfma_f32_16x16x32_bf16(a, b, acc[nt], 0, 0, 0);
    }
  }
  int rb = (l >> 4) * 4;
  int col = l & 15;
#pragma unroll
  for (int nt = 0; nt < 8; nt++) {
    int n = n0 + nt * 16 + col;
    float bv = job.bias ? job.bias[n] : 0.f;
#pragma unroll
    for (int i = 0; i < 4; i++) {
      int m = m0 + rb + i;
      job.outB[(size_t)m * job.N + n] = f2b(acc[nt][i] + bv);
    }
  }
}

// ---------------- persistent sequential loop (3 hops/step, round-12 structure) ----------------

struct LoopP {
  const ushort* whh0b; const ushort* gi0b; const ushort* wh2cb; const ushort* whh1b;
  const ushort* Kp; const ushort* ctxpb;
  const float* bhh0; const float* bih1; const float* bhh1; const float* wmlp;
  const ushort* h0b;
  ushort* h1b;   // TS x B x H   (per-step fresh buffers -> cached reads are safe)
  ushort* hidb;  // TS x B x C
  ushort* gh1b;  // TS x B x 3H
  ushort* H2b;   // TS x B x H
  ushort* flags; // 4 groups x 128-ushort stride (64 used); memset 0 per launch
};

#define FA 0
#define FH 1
#define FG 2
#define FD 3
static __device__ __forceinline__ ushort* flg(ushort* base, int k) { return base + k * 128; }

// producer: drain sc-stores at coherence point, then u16-store step number
static __device__ __forceinline__ void arrive(ushort* slot, unsigned val) {
  asm volatile("s_waitcnt vmcnt(0)" ::: "memory");
  __syncthreads();
  if (threadIdx.x == 0) st_scu16(slot, val);
}
// consumer: 8 lanes x dwordx4 covers all 64 u16 flags
static __device__ __forceinline__ void waitflag(const ushort* slot64, unsigned tgt) {
  __syncthreads();
  if (threadIdx.x < 64) {
    const bool rd = threadIdx.x < 8;
    const ushort* myp = slot64 + threadIdx.x * 8;
    for (;;) {
      int ok = 1;
      if (rd) {
        s8v v = ld_sc16w(myp);
        unsigned mn = 0xFFFFu;
#pragma unroll
        for (int j = 0; j < 8; j++) mn = min(mn, (unsigned)(ushort)v[j]);
        ok = (mn >= tgt);
      }
      if (__all(ok)) break;
      __builtin_amdgcn_s_sleep(4);
    }
  }
  __syncthreads();
}

// roles: 0 (blk 0-63)=GRU0/Whh0 ; 1 (64-127)=hid/Wh2c + fused attn/Ksum/GRU1 ; 2 (128-191)=gh1/Whh1
__global__ __launch_bounds__(256) void k_loop(LoopP p) {
  __shared__ __align__(16) ushort ldsW[48 * 1024];   // 96KB, 48 rows x 2KB, XOR-swizzled
  __shared__ __align__(16) float hs[C_];
  __shared__ float sc[S_];
  __shared__ float al[S_];
  __shared__ __align__(8) ushort stile[64 * 16];     // bf16 epilogue re-layout tile
  __shared__ __align__(8) ushort stile3[64 * 48];    // gh1-role 3-gate re-layout

  const int tid = threadIdx.x;
  const int blk = blockIdx.x;
  const int l = tid & 63, w = tid >> 6;
  const int role = blk >> 6;
  const int sub = blk & 63;

  // ---- stage this block's weight slice into swizzled LDS (once) ----
  {
    const ushort* src;
    int nrows;
    if (role == 0)      { src = p.whh0b; nrows = 48; }
    else if (role == 1) { src = p.wh2cb; nrows = 16; }
    else                { src = p.whh1b; nrows = 48; }
    for (int idx = tid; idx < nrows * 128; idx += 256) {
      int r = idx >> 7, c = idx & 127;
      int grow;
      if (role == 0)      grow = (r >> 4) * H_ + sub * 16 + (r & 15);
      else if (role == 1) grow = sub * 16 + r;
      else                grow = sub * 48 + r;
      s8v v = *reinterpret_cast<const s8v*>(src + (size_t)grow * 1024 + c * 8);
      unsigned o = (unsigned)r * 2048u + (((unsigned)(c * 16)) ^ ((unsigned)((r & 7) << 4)));
      *reinterpret_cast<s8v*>((char*)ldsW + o) = v;
    }
    __syncthreads();
  }

  const int rr = l & 15;
  const int m0 = w * 16;
  const int rb = (l >> 4) * 4, c15 = l & 15;

  for (int t = 0; t < TS_; t++) {
    ushort* h1t  = p.h1b  + (size_t)t * B_ * H_;
    ushort* hidt = p.hidb + (size_t)t * B_ * C_;
    ushort* gh1t = p.gh1b + (size_t)t * B_ * 3 * H_;
    ushort* h2t  = p.H2b  + (size_t)t * B_ * H_;

    if (role == 0) {
      // ---- phase A: h1 = GRU0(h_prev) ----
      if (t) waitflag(flg(p.flags, FD), (unsigned)t);
      const ushort* hpb = t ? (p.H2b + (size_t)(t - 1) * B_ * H_) : p.h0b;
      const ushort* gi0t = p.gi0b + (size_t)t * B_ * 3 * H_;
      int c = sub * 16 + c15;
      f4v aR = {0.f,0.f,0.f,0.f}, aZ = {0.f,0.f,0.f,0.f}, aN = {0.f,0.f,0.f,0.f};
#pragma unroll 4
      for (int kb = 0; kb < H_; kb += 32) {
        s8v a = ldfrag(hpb, H_, m0, kb, l);
        aR = __builtin_amdgcn_mfma_f32_16x16x32_bf16(a, ldsfrag(ldsW, rr, kb, l), aR, 0, 0, 0);
        aZ = __builtin_amdgcn_mfma_f32_16x16x32_bf16(a, ldsfrag(ldsW, 16 + rr, kb, l), aZ, 0, 0, 0);
        aN = __builtin_amdgcn_mfma_f32_16x16x32_bf16(a, ldsfrag(ldsW, 32 + rr, kb, l), aN, 0, 0, 0);
      }
#pragma unroll
      for (int i = 0; i < 4; i++) {
        int m = m0 + rb + i;
        const ushort* gi = gi0t + (size_t)m * (3 * H_);
        float gir = b2f(gi[c]), giz = b2f(gi[H_ + c]), gin = b2f(gi[2 * H_ + c]);
        float ghr = aR[i] + p.bhh0[c], ghz = aZ[i] + p.bhh0[H_ + c], ghn = aN[i] + p.bhh0[2 * H_ + c];
        float r = sigm(gir + ghr);
        float zg = sigm(giz + ghz);
        float nn = tanh_fast(gin + r * ghn);
        float h1 = (1.f - zg) * nn + zg * b2f(hpb[(size_t)m * H_ + c]);
        stile[m * 16 + c15] = f2b(h1);
      }
      __syncthreads();
      {
        int row = tid >> 2, ch = tid & 3;
        u64 v = *reinterpret_cast<u64*>(&stile[row * 16 + ch * 4]);
        st_sc8(&h1t[(size_t)row * H_ + sub * 16 + ch * 4], v);
      }
      arrive(flg(p.flags, FA) + sub, (unsigned)(t + 1));

    } else if (role == 1) {
      // ---- hid = h1 @ Wh2c.T (16-col slice) ----
      waitflag(flg(p.flags, FA), (unsigned)(t + 1));
      {
        f4v acc = {0.f,0.f,0.f,0.f};
#pragma unroll 4
        for (int kb = 0; kb < H_; kb += 32) {
          s8v a = ldfrag(h1t, H_, m0, kb, l);
          acc = __builtin_amdgcn_mfma_f32_16x16x32_bf16(a, ldsfrag(ldsW, rr, kb, l), acc, 0, 0, 0);
        }
#pragma unroll
        for (int i = 0; i < 4; i++) stile[(m0 + rb + i) * 16 + c15] = f2b(acc[i]);
        __syncthreads();
        int row = tid >> 2, ch = tid & 3;
        u64 v = *reinterpret_cast<u64*>(&stile[row * 16 + ch * 4]);
        st_sc8(&hidt[(size_t)row * C_ + sub * 16 + ch * 4], v);
      }
      arrive(flg(p.flags, FH) + sub, (unsigned)(t + 1));

      // ---- fused: attention + K-weighted-sum + GRU1 epilogue (b = sub) ----
      waitflag(flg(p.flags, FH), (unsigned)(t + 1));
      {
        int b = sub;
        s8v hv8 = *reinterpret_cast<const s8v*>(hidt + (size_t)b * C_ + tid * 8);
#pragma unroll
        for (int j = 0; j < 8; j++) hs[tid * 8 + j] = b2f((ushort)hv8[j]);
        __syncthreads();
        for (int s = w; s < S_; s += 4) {
          const ushort* row = p.ctxpb + ((size_t)s * B_ + b) * C_;
          float a = 0.f;
          for (int c4 = l * 4; c4 < C_; c4 += 256) {
            ushort4 cv = *reinterpret_cast<const ushort4*>(row + c4);
            f4v hv4 = *reinterpret_cast<const f4v*>(&hs[c4]);
            float4 wv = *reinterpret_cast<const float4*>(p.wmlp + c4);
            a += tanh_fast(b2f(cv.x) + hv4[0]) * wv.x;
            a += tanh_fast(b2f(cv.y) + hv4[1]) * wv.y;
            a += tanh_fast(b2f(cv.z) + hv4[2]) * wv.z;
            a += tanh_fast(b2f(cv.w) + hv4[3]) * wv.w;
          }
          for (int m = 32; m; m >>= 1) a += __shfl_xor(a, m, 64);
          if (l == 0) sc[s] = a;
        }
        __syncthreads();
        float mx = -1e30f;
        for (int s = 0; s < S_; s++) mx = fmaxf(mx, sc[s]);
        float sm = 0.f;
        for (int s = 0; s < S_; s++) sm += __expf(sc[s] - mx);
        if (tid < S_) al[tid] = __expf(sc[tid] - mx) / sm;
        __syncthreads();

        int c0 = tid * 4;
        // gi1 = sum_s al[s] * K[b,g,s,:] — only needs al + prologue Kp => BEFORE the FG wait
        const ushort* kb0 = p.Kp + (size_t)b * 153600 + c0;   // 3*50*1024 per b
        float rc0=0.f,rc1=0.f,rc2=0.f,rc3=0.f, zc0=0.f,zc1=0.f,zc2=0.f,zc3=0.f,
              nc0=0.f,nc1=0.f,nc2=0.f,nc3=0.f;
#pragma unroll 2
        for (int s = 0; s < S_; s++) {
          float a = al[s];
          ushort4 kr = *reinterpret_cast<const ushort4*>(kb0 + s * 1024);
          ushort4 kz = *reinterpret_cast<const ushort4*>(kb0 + 51200 + s * 1024);
          ushort4 kn = *reinterpret_cast<const ushort4*>(kb0 + 102400 + s * 1024);
          rc0 += a * b2f(kr.x); rc1 += a * b2f(kr.y); rc2 += a * b2f(kr.z); rc3 += a * b2f(kr.w);
          zc0 += a * b2f(kz.x); zc1 += a * b2f(kz.y); zc2 += a * b2f(kz.z); zc3 += a * b2f(kz.w);
          nc0 += a * b2f(kn.x); nc1 += a * b2f(kn.y); nc2 += a * b2f(kn.z); nc3 += a * b2f(kn.w);
        }

        waitflag(flg(p.flags, FG), (unsigned)(t + 1));   // gh1 ready (overlapped by K-sum)

        u64 ghr8 = *reinterpret_cast<const u64*>(&gh1t[(size_t)b * 3072 + c0]);
        u64 ghz8 = *reinterpret_cast<const u64*>(&gh1t[(size_t)b * 3072 + 1024 + c0]);
        u64 ghn8 = *reinterpret_cast<const u64*>(&gh1t[(size_t)b * 3072 + 2048 + c0]);
        u64 h18  = *reinterpret_cast<const u64*>(&h1t[(size_t)b * 1024 + c0]);
        float rcv[4] = {rc0, rc1, rc2, rc3};
        float zcv[4] = {zc0, zc1, zc2, zc3};
        float ncv[4] = {nc0, nc1, nc2, nc3};
        u64 outp = 0;
#pragma unroll
        for (int j = 0; j < 4; j++) {
          int c = c0 + j;
          float gir = rcv[j] + p.bih1[c];
          float giz = zcv[j] + p.bih1[H_ + c];
          float gin = ncv[j] + p.bih1[2 * H_ + c];
          float ghr = b2f((ushort)(ghr8 >> (16 * j))) + p.bhh1[c];
          float ghz = b2f((ushort)(ghz8 >> (16 * j))) + p.bhh1[H_ + c];
          float ghn = b2f((ushort)(ghn8 >> (16 * j))) + p.bhh1[2 * H_ + c];
          float r = sigm(gir + ghr);
          float zg = sigm(giz + ghz);
          float nn = tanh_fast(gin + r * ghn);
          float h1v = b2f((ushort)(h18 >> (16 * j)));
          float h2 = (1.f - zg) * nn + zg * h1v;
          outp |= (u64)f2b(h2) << (16 * j);
        }
        st_sc8(&h2t[(size_t)b * 1024 + c0], outp);
      }
      arrive(flg(p.flags, FD) + sub, (unsigned)(t + 1));

    } else {
      // ---- gh1 = h1 @ Whh1.T (48-col slice) -> bf16 ----
      waitflag(flg(p.flags, FA), (unsigned)(t + 1));
      {
        f4v aR = {0.f,0.f,0.f,0.f}, aZ = {0.f,0.f,0.f,0.f}, aN = {0.f,0.f,0.f,0.f};
#pragma unroll 4
        for (int kb = 0; kb < H_; kb += 32) {
          s8v a = ldfrag(h1t, H_, m0, kb, l);
          aR = __builtin_amdgcn_mfma_f32_16x16x32_bf16(a, ldsfrag(ldsW, rr, kb, l), aR, 0, 0, 0);
          aZ = __builtin_amdgcn_mfma_f32_16x16x32_bf16(a, ldsfrag(ldsW, 16 + rr, kb, l), aZ, 0, 0, 0);
          aN = __builtin_amdgcn_mfma_f32_16x16x32_bf16(a, ldsfrag(ldsW, 32 + rr, kb, l), aN, 0, 0, 0);
        }
#pragma unroll
        for (int i = 0; i < 4; i++) {
          int m = m0 + rb + i;
          stile3[m * 48 + c15]      = f2b(aR[i]);
          stile3[m * 48 + 16 + c15] = f2b(aZ[i]);
          stile3[m * 48 + 32 + c15] = f2b(aN[i]);
        }
        __syncthreads();
#pragma unroll
        for (int j = 0; j < 3; j++) {
          int idx = tid + 256 * j;
          int row = idx / 12, k = idx % 12, lc4 = k * 4;
          u64 v = *reinterpret_cast<u64*>(&stile3[row * 48 + lc4]);
          st_sc8(&gh1t[(size_t)row * (3 * H_) + (lc4 >> 4) * H_ + sub * 16 + (lc4 & 15)], v);
        }
      }
      arrive(flg(p.flags, FG) + sub, (unsigned)(t + 1));
    }
  }
}

// ---------------- epilogue: streaming LSE over vocab (2 row-tiles per wave) ----------------
#define LSE_NCH 40
#define LSE_TILES 50    // 16-col tiles per chunk (40*50*16 = 32000)

__global__ __launch_bounds__(512) void k_lse2(const ushort* __restrict__ logitb,
                                              const ushort* __restrict__ wopb,
                                              const float* __restrict__ bop,
                                              float* __restrict__ part) {
  __shared__ ushort Bs[2][16 * E_];   // 2 x 16KB (16 rows x 1024B)
  int tid = threadIdx.x, l = tid & 63, w = tid >> 6;
  int r0 = blockIdx.y * 256 + w * 32;            // each wave: rows r0..r0+31 (2 tiles)
  int c0 = blockIdx.x * (LSE_TILES * 16);
  int arow0 = r0 + (l & 15);
  int arow1 = arow0 + 16;
  bool aok0 = arow0 < NR_, aok1 = arow1 < NR_;

  s8v afr0[16], afr1[16];
#pragma unroll
  for (int kk = 0; kk < 16; kk++) {
    s8v z = {0,0,0,0,0,0,0,0};
    afr0[kk] = aok0 ? *reinterpret_cast<const s8v*>(logitb + (size_t)arow0 * E_ + kk * 32 + ((l >> 4) << 3)) : z;
    afr1[kk] = aok1 ? *reinterpret_cast<const s8v*>(logitb + (size_t)arow1 * E_ + kk * 32 + ((l >> 4) << 3)) : z;
  }

  const int srow = tid >> 5;
  const int scb = (tid & 31) * 32;
  const unsigned sxr = (unsigned)((srow & 7) << 4);
  char* sdst0 = (char*)&Bs[0][0] + srow * 1024;
  char* sdst1 = (char*)&Bs[1][0] + srow * 1024;

  const int brow = l & 15;
  const unsigned lanep = (unsigned)((l >> 4) << 4);
  const unsigned xorv = (unsigned)((brow & 7) << 4);
  const char* bbase0 = (const char*)&Bs[0][0] + brow * 1024;
  const char* bbase1 = (const char*)&Bs[1][0] + brow * 1024;

  f4v mr0 = {-1e30f, -1e30f, -1e30f, -1e30f}, mr1 = mr0;
  f4v sr0 = {0.f, 0.f, 0.f, 0.f}, sr1 = sr0;

  {
    const char* src = (const char*)(wopb + (size_t)(c0 + srow) * E_) + scb;
    s8v g0 = *reinterpret_cast<const s8v*>(src);
    s8v g1 = *reinterpret_cast<const s8v*>(src + 16);
    *reinterpret_cast<s8v*>(sdst0 + ((unsigned)scb ^ sxr)) = g0;
    *reinterpret_cast<s8v*>(sdst0 + (((unsigned)scb + 16u) ^ sxr)) = g1;
  }
  __syncthreads();

  for (int tt = 0; tt < LSE_TILES; tt++) {
    int cur = tt & 1;
    bool more = (tt + 1) < LSE_TILES;
    s8v g0, g1;
    if (more) {
      const char* src = (const char*)(wopb + (size_t)(c0 + (tt + 1) * 16 + srow) * E_) + scb;
      g0 = *reinterpret_cast<const s8v*>(src);
      g1 = *reinterpret_cast<const s8v*>(src + 16);
    }
    const char* bbase = cur ? bbase1 : bbase0;
    f4v acc0 = {0.f, 0.f, 0.f, 0.f}, acc1 = {0.f, 0.f, 0.f, 0.f};
#pragma unroll
    for (int kk = 0; kk < 16; kk++) {
      unsigned off = ((unsigned)(kk * 64) + lanep) ^ xorv;
      s8v b = *reinterpret_cast<const s8v*>(bbase + off);
      acc0 = __builtin_amdgcn_mfma_f32_16x16x32_bf16(afr0[kk], b, acc0, 0, 0, 0);
      acc1 = __builtin_amdgcn_mfma_f32_16x16x32_bf16(afr1[kk], b, acc1, 0, 0, 0);
    }
    float bv = bop[c0 + tt * 16 + (l & 15)];
#pragma unroll
    for (int i = 0; i < 4; i++) {
      float v0 = acc0[i] + bv;
      if (v0 <= mr0[i]) {
        sr0[i] += __expf(v0 - mr0[i]);
      } else {
        sr0[i] = sr0[i] * __expf(mr0[i] - v0) + 1.f;
        mr0[i] = v0;
      }
      float v1 = acc1[i] + bv;
      if (v1 <= mr1[i]) {
        sr1[i] += __expf(v1 - mr1[i]);
      } else {
        sr1[i] = sr1[i] * __expf(mr1[i] - v1) + 1.f;
        mr1[i] = v1;
      }
    }
    if (more) {
      char* sdst = cur ? sdst0 : sdst1;
      *reinterpret_cast<s8v*>(sdst + ((unsigned)scb ^ sxr)) = g0;
      *reinterpret_cast<s8v*>(sdst + (((unsigned)scb + 16u) ^ sxr)) = g1;
      __syncthreads();
    }
  }

  for (int sh = 1; sh < 16; sh <<= 1) {
#pragma unroll
    for (int i = 0; i < 4; i++) {
      float om0 = __shfl_xor(mr0[i], sh, 64);
      float os0 = __shfl_xor(sr0[i], sh, 64);
      float mn0 = fmaxf(mr0[i], om0);
      sr0[i] = sr0[i] * __expf(mr0[i] - mn0) + os0 * __expf(om0 - mn0);
      mr0[i] = mn0;
      float om1 = __shfl_xor(mr1[i], sh, 64);
      float os1 = __shfl_xor(sr1[i], sh, 64);
      float mn1 = fmaxf(mr1[i], om1);
      sr1[i] = sr1[i] * __expf(mr1[i] - mn1) + os1 * __expf(om1 - mn1);
      mr1[i] = mn1;
    }
  }
  if ((l & 15) == 0) {
#pragma unroll
    for (int i = 0; i < 4; i++) {
      int row0 = r0 + (l >> 4) * 4 + i;
      if (row0 < NR_) {
        size_t o = ((size_t)row0 * LSE_NCH + blockIdx.x) * 2;
        part[o] = mr0[i];
        part[o + 1] = sr0[i];
      }
      int row1 = row0 + 16;
      if (row1 < NR_) {
        size_t o = ((size_t)row1 * LSE_NCH + blockIdx.x) * 2;
        part[o] = mr1[i];
        part[o + 1] = sr1[i];
      }
    }
  }
}

__global__ void k_final(const float* __restrict__ part, const ushort* __restrict__ logitb,
                        const float* __restrict__ Wop, const float* __restrict__ bop,
                        const int* __restrict__ y, float* __restrict__ nll) {
  int i = blockIdx.x * 256 + threadIdx.x;
  if (i >= NR_) return;
  float m = -1e30f;
  for (int c = 0; c < LSE_NCH; c++) m = fmaxf(m, part[((size_t)i * LSE_NCH + c) * 2]);
  float s = 0.f;
  for (int c = 0; c < LSE_NCH; c++) {
    size_t o = ((size_t)i * LSE_NCH + c) * 2;
    s += part[o + 1] * __expf(part[o] - m);
  }
  float lse = m + logf(s);
  int tgt = y[i + B_];
  float v = 0.f;
  if (tgt != 0) {
    const ushort* lr = logitb + (size_t)i * E_;
    const float* wr = Wop + (size_t)tgt * E_;
    float dot = 0.f;
    for (int k = 0; k < E_; k += 4) {
      ushort4 lv = *reinterpret_cast<const ushort4*>(lr + k);
      float4 wv = *reinterpret_cast<const float4*>(wr + k);
      dot += b2f(lv.x) * wv.x + b2f(lv.y) * wv.y + b2f(lv.z) * wv.z + b2f(lv.w) * wv.w;
    }
    dot += bop[tgt];
    v = lse - dot;
  }
  nll[i] = v;
}

__global__ void k_reduce(const float* __restrict__ nll, float* __restrict__ out) {
  __shared__ float sh[256];
  float a = 0.f;
  for (int i = threadIdx.x; i < NR_; i += 256) a += nll[i];
  sh[threadIdx.x] = a;
  __syncthreads();
  for (int s = 128; s; s >>= 1) {
    if (threadIdx.x < s) sh[threadIdx.x] += sh[threadIdx.x + s];
    __syncthreads();
  }
  if (threadIdx.x == 0) out[0] = sh[0];
}

// ---------------- host ----------------

extern "C" void kernel_launch(void* const* d_in, const int* in_sizes, int n_in,
                              void* d_out, int out_size, void* d_ws, size_t ws_size,
                              hipStream_t stream) {
  const float* ctx  = (const float*)d_in[0];
  const int*   y    = (const int*)d_in[1];
  const float* emb  = (const float*)d_in[2];
  const float* Wih0 = (const float*)d_in[3];
  const float* Whh0 = (const float*)d_in[4];
  const float* bih0 = (const float*)d_in[5];
  const float* bhh0 = (const float*)d_in[6];
  const float* Wih1 = (const float*)d_in[7];
  const float* Whh1 = (const float*)d_in[8];
  const float* bih1 = (const float*)d_in[9];
  const float* bhh1 = (const float*)d_in[10];
  const float* Wc2c = (const float*)d_in[11];
  const float* Wh2c = (const float*)d_in[12];
  const float* wmlp = (const float*)d_in[13];
  const float* Wc2h = (const float*)d_in[14];
  const float* Who  = (const float*)d_in[15];
  const float* bho  = (const float*)d_in[16];
  const float* Wop  = (const float*)d_in[17];
  const float* bop  = (const float*)d_in[18];

  char* ws = (char*)d_ws;
  size_t off = 0;
  auto alloc = [&](size_t bytes) { void* p = ws + off; off += (bytes + 4095) & ~size_t(4095); return p; };

  ushort* ctxb   = (ushort*)alloc((size_t)S_ * B_ * C_ * 2);
  ushort* wih0b  = (ushort*)alloc((size_t)3 * H_ * E_ * 2);
  ushort* whh0b  = (ushort*)alloc((size_t)3 * H_ * H_ * 2);
  ushort* wh2cb  = (ushort*)alloc((size_t)C_ * H_ * 2);
  ushort* wc2hT  = (ushort*)alloc((size_t)C_ * H_ * 2);
  ushort* wih1b  = (ushort*)alloc((size_t)3 * H_ * H_ * 2);
  ushort* whh1b  = (ushort*)alloc((size_t)3 * H_ * H_ * 2);
  ushort* whob   = (ushort*)alloc((size_t)E_ * H_ * 2);
  ushort* wopb   = (ushort*)alloc((size_t)V_ * E_ * 2);
  ushort* wc2cb  = (ushort*)alloc((size_t)C_ * C_ * 2);
  ushort* wcombb = (ushort*)alloc((size_t)3 * H_ * C_ * 2);
  ushort* Kp     = (ushort*)alloc((size_t)S_ * B_ * 3 * H_ * 2);
  ushort* xb     = (ushort*)alloc((size_t)NR_ * E_ * 2);
  ushort* gi0b   = (ushort*)alloc((size_t)NR_ * 3 * H_ * 2);
  ushort* ctxpb  = (ushort*)alloc((size_t)S_ * B_ * C_ * 2);
  ushort* H2b    = (ushort*)alloc((size_t)TS_ * B_ * H_ * 2);
  ushort* h0b    = (ushort*)alloc((size_t)B_ * H_ * 2);
  ushort* h1b    = (ushort*)alloc((size_t)TS_ * B_ * H_ * 2);
  ushort* hidb   = (ushort*)alloc((size_t)TS_ * B_ * C_ * 2);
  ushort* gh1b   = (ushort*)alloc((size_t)TS_ * B_ * 3 * H_ * 2);
  ushort* logitb = (ushort*)alloc((size_t)NR_ * E_ * 2);
  float*  part   = (float*)alloc((size_t)2048 * LSE_NCH * 2 * 4);
  float*  nllb   = (float*)alloc((size_t)2048 * 4);
  ushort* flags  = (ushort*)alloc(4 * 128 * 2);
  (void)ws_size; (void)in_sizes; (void)n_in; (void)out_size;

  (void)hipMemsetAsync(h0b, 0, (size_t)B_ * H_ * 2, stream);
  (void)hipMemsetAsync(flags, 0, 4 * 128 * 2, stream);

  // fused prologue: 9 converts + 1 transpose + gather
  PrepP pp;
  auto seg = [&](int i, const float* s, ushort* d, size_t n) {
    pp.seg[i].s = s; pp.seg[i].d = d; pp.seg[i].n4 = (unsigned)(n / 4);
  };
  seg(0, ctx, ctxb, (size_t)S_ * B_ * C_);
  seg(1, Wih0, wih0b, (size_t)3 * H_ * E_);
  seg(2, Whh0, whh0b, (size_t)3 * H_ * H_);
  seg(3, Wih1, wih1b, (size_t)3 * H_ * H_);
  seg(4, Whh1, whh1b, (size_t)3 * H_ * H_);
  seg(5, Who, whob, (size_t)E_ * H_);
  seg(6, Wop, wopb, (size_t)V_ * E_);
  seg(7, Wc2c, wc2cb, (size_t)C_ * C_);
  seg(8, Wh2c, wh2cb, (size_t)C_ * H_);
  unsigned t0 = 0;
  for (int i = 0; i < 9; i++) t0 += pp.seg[i].n4;
  pp.tot0 = t0;
  pp.tot1 = t0 + (unsigned)(H_ * C_);
  pp.tot2 = pp.tot1 + (unsigned)(NR_ * (E_ / 4));
  pp.Wc2h = Wc2h; pp.wc2hT = wc2hT;
  pp.y = y; pp.emb = emb; pp.xb = xb;
  k_prep<<<dim3(2048), 256, 0, stream>>>(pp);

  // 3 independent GEMMs in one dispatch: gi0, ctxp, wcomb
  GMulti gm;
  gm.j[0] = { xb,    wih0b, bih0,    gi0b,   3 * H_, E_, (3 * H_) / 128, 0 };
  gm.j[1] = { ctxb,  wc2cb, nullptr, ctxpb,  C_,     C_, C_ / 128,       (unsigned)((3 * H_ / 128) * (NR_ / 64)) };
  gm.j[2] = { wih1b, wc2hT, nullptr, wcombb, C_,     H_, C_ / 128,       gm.j[1].blk0 + (unsigned)((C_ / 128) * (S_ * B_ / 64)) };
  unsigned gtot = gm.j[2].blk0 + (unsigned)((C_ / 128) * (3 * H_ / 64));
  gemm_multi<<<dim3(gtot), 256, 0, stream>>>(gm);

  // K = ctx @ W_comb.T, written in [b][gate][s][c] layout (kperm=1)
  gemm_bt<<<dim3(3 * H_ / 128, S_ * B_ / 64), 256, 0, stream>>>(ctxb, wcombb, nullptr, Kp,
                                                                S_ * B_, 3 * H_, C_, 0, 1);

  LoopP p;
  p.whh0b = whh0b; p.gi0b = gi0b; p.wh2cb = wh2cb; p.whh1b = whh1b;
  p.Kp = Kp; p.ctxpb = ctxpb;
  p.bhh0 = bhh0; p.bih1 = bih1; p.bhh1 = bhh1; p.wmlp = wmlp;
  p.h0b = h0b;
  p.h1b = h1b; p.hidb = hidb; p.gh1b = gh1b;
  p.H2b = H2b; p.flags = flags;
  void* args[] = { (void*)&p };
  (void)hipLaunchCooperativeKernel(k_loop, dim3(NBLK_), dim3(256), args, 0, stream);

  gemm_bt<<<dim3(E_ / 128, NR_ / 64), 256, 0, stream>>>(H2b, whob, bho, logitb,
                                                        NR_, E_, H_, 1, 0);
  k_lse2<<<dim3(LSE_NCH, 8), 512, 0, stream>>>(logitb, wopb, bop, part);
  k_final<<<dim3(8), 256, 0, stream>>>(part, logitb, Wop, bop, y, nllb);
  k_reduce<<<dim3(1), 256, 0, stream>>>(nllb, (float*)d_out);
}

// Round 15
// 2199.434 us; speedup vs baseline: 1.5285x; 1.0004x over previous
//
#include <hip/hip_runtime.h>

#define S_ 50
#define B_ 64
#define T_ 32
#define E_ 512
#define H_ 1024
#define C_ 1024
#define V_ 32000
#define TS_ 31            // T-1 steps
#define NR_ 1984          // TS_*B_ rows
#define NBLK_ 192         // persistent-loop grid size (3 roles x 64)

typedef __attribute__((ext_vector_type(8))) short s8v;   // 8 x bf16 bits
typedef __attribute__((ext_vector_type(4))) float f4v;   // MFMA acc / float4
typedef unsigned long long u64;

static __device__ __forceinline__ float b2f(ushort u) {
  unsigned x = ((unsigned)u) << 16; float f; __builtin_memcpy(&f, &x, 4); return f;
}
static __device__ __forceinline__ ushort f2b(float f) {
  unsigned x; __builtin_memcpy(&x, &f, 4);
  x = x + 0x7FFFu + ((x >> 16) & 1u);
  return (ushort)(x >> 16);
}
// f32 -> OCP e4m3fn, RNE, saturate to 448
static __device__ __forceinline__ unsigned char f2e4m3(float f) {
  unsigned u; __builtin_memcpy(&u, &f, 4);
  unsigned s = (u >> 24) & 0x80u;
  float a = fabsf(f);
  if (a > 448.f) a = 448.f;
  unsigned out;
  if (a < 0.015625f) {               // denormal target (step 2^-9); rint handles round-to-normal-min
    out = (unsigned)(int)rintf(a * 512.f);
  } else {
    __builtin_memcpy(&u, &a, 4);
    unsigned u2 = u + 0x7FFFFu + ((u >> 20) & 1u);   // RNE at 3 mantissa bits
    int e2 = (int)((u2 >> 23) & 0xFF) - 127;
    unsigned mant = (u2 >> 20) & 7u;
    int E = e2 + 7;
    if (E > 15) { E = 15; mant = 7; }
    out = ((unsigned)E << 3) | mant;
  }
  return (unsigned char)(out | s);
}
static __device__ __forceinline__ float sigm(float x) { return 1.f / (1.f + __expf(-x)); }
static __device__ __forceinline__ float tanh_fast(float x) {
  float e = __expf(2.f * x);
  return 1.f - 2.f / (e + 1.f);
}

// ---- coherence-point I/O: producers publish via sc0 sc1; flags re-read uncached ----
static __device__ __forceinline__ s8v ld_sc16w(const void* p) {
  s8v v;
  asm volatile("global_load_dwordx4 %0, %1, off sc0 sc1\n\ts_waitcnt vmcnt(0)"
               : "=&v"(v) : "v"(p) : "memory");
  return v;
}
static __device__ __forceinline__ void st_sc8(void* p, u64 v) {
  asm volatile("global_store_dwordx2 %0, %1, off sc0 sc1" :: "v"(p), "v"(v) : "memory");
}
static __device__ __forceinline__ void st_scu16(ushort* p, unsigned v) {
  asm volatile("global_store_short %0, %1, off sc0 sc1" :: "v"(p), "v"(v) : "memory");
}

// A-frag: lane holds row (l&15), k = kb + 8*(l>>4) + j   (16B contiguous cached load)
static __device__ __forceinline__ s8v ldfrag(const ushort* base, int ld, int row0, int kb, int lane) {
  const ushort* p = base + (size_t)(row0 + (lane & 15)) * ld + (kb + ((lane >> 4) << 3));
  return *reinterpret_cast<const s8v*>(p);
}

// B-frag from swizzled LDS: row r (2KB rows), byte col = kb*2 + (l>>4)*16, XOR (r&7)<<4
static __device__ __forceinline__ s8v ldsfrag(const ushort* base, int r, int kb, int lane) {
  unsigned o = (unsigned)r * 2048u +
               (((unsigned)(kb * 2 + ((lane >> 4) << 4))) ^ ((unsigned)((r & 7) << 4)));
  return *reinterpret_cast<const s8v*>((const char*)base + o);
}

// ---------------- fused prologue: converts + transpose + gather + wop-fp8 (one dispatch) ----------------

struct CvtSeg { const float* s; ushort* d; unsigned n4; };
struct PrepP {
  CvtSeg seg[8];
  const float* Wc2h; ushort* wc2hT;   // wc2hT[c*1024+h] = Wc2h[h*1024+c]
  const int* y; const float* emb; ushort* xb;
  const float* Wop; unsigned char* wop8;   // wop8 = fp8(4*Wop)
  unsigned tot0, tot1, tot2, tot3;    // cumulative region ends
};

__global__ void k_prep(PrepP pp) {
  for (unsigned q = blockIdx.x * 256 + threadIdx.x; q < pp.tot3; q += gridDim.x * 256) {
    if (q < pp.tot0) {
      unsigned off = q;
      int s = 0;
      while (off >= pp.seg[s].n4) { off -= pp.seg[s].n4; s++; }
      float4 v = reinterpret_cast<const float4*>(pp.seg[s].s)[off];
      ushort4 o; o.x = f2b(v.x); o.y = f2b(v.y); o.z = f2b(v.z); o.w = f2b(v.w);
      reinterpret_cast<ushort4*>(pp.seg[s].d)[off] = o;
    } else if (q < pp.tot1) {
      unsigned g = q - pp.tot0;
      int h = g & 1023, c = g >> 10;
      pp.wc2hT[(size_t)c * 1024 + h] = f2b(pp.Wc2h[(size_t)h * 1024 + c]);
    } else if (q < pp.tot2) {
      unsigned g = q - pp.tot1;
      int i = g >> 7;
      int c = (g & 127) << 2;
      int idx = pp.y[i];
      float4 v = make_float4(0.f, 0.f, 0.f, 0.f);
      if (idx != 0) v = *reinterpret_cast<const float4*>(pp.emb + (size_t)idx * E_ + c);
      ushort4 o; o.x = f2b(v.x); o.y = f2b(v.y); o.z = f2b(v.z); o.w = f2b(v.w);
      *reinterpret_cast<ushort4*>(pp.xb + (size_t)i * E_ + c) = o;
    } else {
      unsigned g = q - pp.tot2;
      float4 v = reinterpret_cast<const float4*>(pp.Wop)[g];
      uchar4 o;
      o.x = f2e4m3(v.x * 4.f); o.y = f2e4m3(v.y * 4.f);
      o.z = f2e4m3(v.z * 4.f); o.w = f2e4m3(v.w * 4.f);
      reinterpret_cast<uchar4*>(pp.wop8)[g] = o;
    }
  }
}

// ---------------- generic GEMM: out[m,n]=sum_k A[m,k]*B[n,k] (+bias)(opt tanh), 64x128 blocks ----
// kperm=1: write outB in K-permuted layout [b][gate][s][c]; out8: optional fp8(4*v) copy
__global__ void gemm_bt(const ushort* __restrict__ A, const ushort* __restrict__ Bm,
                        const float* __restrict__ bias, ushort* __restrict__ outB,
                        unsigned char* __restrict__ out8,
                        int M, int N, int K, int act, int kperm) {
  int l = threadIdx.x & 63, w = threadIdx.x >> 6;
  int m0 = blockIdx.y * 64 + w * 16;
  int n0 = blockIdx.x * 128;
  f4v acc[8] = {{0.f,0.f,0.f,0.f},{0.f,0.f,0.f,0.f},{0.f,0.f,0.f,0.f},{0.f,0.f,0.f,0.f},
                {0.f,0.f,0.f,0.f},{0.f,0.f,0.f,0.f},{0.f,0.f,0.f,0.f},{0.f,0.f,0.f,0.f}};
  for (int kb = 0; kb < K; kb += 32) {
    s8v a = ldfrag(A, K, m0, kb, l);
#pragma unroll
    for (int nt = 0; nt < 8; nt++) {
      s8v b = ldfrag(Bm, K, n0 + nt * 16, kb, l);
      acc[nt] = __builtin_amdgcn_mfma_f32_16x16x32_bf16(a, b, acc[nt], 0, 0, 0);
    }
  }
  int rb = (l >> 4) * 4;
  int col = l & 15;
#pragma unroll
  for (int nt = 0; nt < 8; nt++) {
    int n = n0 + nt * 16 + col;
    float bv = bias ? bias[n] : 0.f;
#pragma unroll
    for (int i = 0; i < 4; i++) {
      int m = m0 + rb + i;
      float v = acc[nt][i] + bv;
      if (act) v = tanhf(v);
      size_t o;
      if (kperm) {
        int bq = m & 63, sq = m >> 6, g = n >> 10, cc = n & 1023;
        o = (((size_t)bq * 3 + g) * 50 + sq) * 1024 + cc;
      } else {
        o = (size_t)m * N + n;
      }
      outB[o] = f2b(v);
      if (out8) out8[(size_t)m * N + n] = f2e4m3(v * 4.f);
    }
  }
}

// 3 independent GEMMs in one dispatch (gi0, ctxp, wcomb)
struct GJob { const ushort* A; const ushort* B; const float* bias; ushort* outB;
              int N, K, nbx; unsigned blk0; };
struct GMulti { GJob j[3]; };

__global__ void gemm_multi(GMulti g) {
  int blk = blockIdx.x;
  int jb = (blk >= (int)g.j[2].blk0) ? 2 : ((blk >= (int)g.j[1].blk0) ? 1 : 0);
  GJob job = g.j[jb];
  unsigned local = blk - job.blk0;
  int by = local / job.nbx, bx = local % job.nbx;
  int l = threadIdx.x & 63, w = threadIdx.x >> 6;
  int m0 = by * 64 + w * 16;
  int n0 = bx * 128;
  f4v acc[8] = {{0.f,0.f,0.f,0.f},{0.f,0.f,0.f,0.f},{0.f,0.f,0.f,0.f},{0.f,0.f,0.f,0.f},
                {0.f,0.f,0.f,0.f},{0.f,0.f,0.f,0.f},{0.f,0.f,0.f,0.f},{0.f,0.f,0.f,0.f}};
  for (int kb = 0; kb < job.K; kb += 32) {
    s8v a = ldfrag(job.A, job.K, m0, kb, l);
#pragma unroll
    for (int nt = 0; nt < 8; nt++) {
      s8v b = ldfrag(job.B, job.K, n0 + nt * 16, kb, l);
      acc[nt] = __builtin_amdgcn_mfma_f32_16x16x32_bf16(a, b, acc[nt], 0, 0, 0);
    }
  }
  int rb = (l >> 4) * 4;
  int col = l & 15;
#pragma unroll
  for (int nt = 0; nt < 8; nt++) {
    int n = n0 + nt * 16 + col;
    float bv = job.bias ? job.bias[n] : 0.f;
#pragma unroll
    for (int i = 0; i < 4; i++) {
      int m = m0 + rb + i;
      job.outB[(size_t)m * job.N + n] = f2b(acc[nt][i] + bv);
    }
  }
}

// ---------------- persistent sequential loop (3 hops/step, round-12 structure) ----------------

struct LoopP {
  const ushort* whh0b; const ushort* gi0b; const ushort* wh2cb; const ushort* whh1b;
  const ushort* Kp; const ushort* ctxpb;
  const float* bhh0; const float* bih1; const float* bhh1; const float* wmlp;
  const ushort* h0b;
  ushort* h1b;   // TS x B x H   (per-step fresh buffers -> cached reads are safe)
  ushort* hidb;  // TS x B x C
  ushort* gh1b;  // TS x B x 3H
  ushort* H2b;   // TS x B x H
  ushort* flags; // 4 groups x 128-ushort stride (64 used); memset 0 per launch
};

#define FA 0
#define FH 1
#define FG 2
#define FD 3
static __device__ __forceinline__ ushort* flg(ushort* base, int k) { return base + k * 128; }

// producer: drain sc-stores at coherence point, then u16-store step number
static __device__ __forceinline__ void arrive(ushort* slot, unsigned val) {
  asm volatile("s_waitcnt vmcnt(0)" ::: "memory");
  __syncthreads();
  if (threadIdx.x == 0) st_scu16(slot, val);
}
// consumer: 8 lanes x dwordx4 covers all 64 u16 flags
static __device__ __forceinline__ void waitflag(const ushort* slot64, unsigned tgt) {
  __syncthreads();
  if (threadIdx.x < 64) {
    const bool rd = threadIdx.x < 8;
    const ushort* myp = slot64 + threadIdx.x * 8;
    for (;;) {
      int ok = 1;
      if (rd) {
        s8v v = ld_sc16w(myp);
        unsigned mn = 0xFFFFu;
#pragma unroll
        for (int j = 0; j < 8; j++) mn = min(mn, (unsigned)(ushort)v[j]);
        ok = (mn >= tgt);
      }
      if (__all(ok)) break;
      __builtin_amdgcn_s_sleep(4);
    }
  }
  __syncthreads();
}

// roles: 0 (blk 0-63)=GRU0/Whh0 ; 1 (64-127)=hid/Wh2c + fused attn/Ksum/GRU1 ; 2 (128-191)=gh1/Whh1
__global__ __launch_bounds__(256) void k_loop(LoopP p) {
  __shared__ __align__(16) ushort ldsW[48 * 1024];   // 96KB, 48 rows x 2KB, XOR-swizzled
  __shared__ __align__(16) float hs[C_];
  __shared__ float sc[S_];
  __shared__ float al[S_];
  __shared__ __align__(8) ushort stile[64 * 16];     // bf16 epilogue re-layout tile
  __shared__ __align__(8) ushort stile3[64 * 48];    // gh1-role 3-gate re-layout

  const int tid = threadIdx.x;
  const int blk = blockIdx.x;
  const int l = tid & 63, w = tid >> 6;
  const int role = blk >> 6;
  const int sub = blk & 63;

  // ---- stage this block's weight slice into swizzled LDS (once) ----
  {
    const ushort* src;
    int nrows;
    if (role == 0)      { src = p.whh0b; nrows = 48; }
    else if (role == 1) { src = p.wh2cb; nrows = 16; }
    else                { src = p.whh1b; nrows = 48; }
    for (int idx = tid; idx < nrows * 128; idx += 256) {
      int r = idx >> 7, c = idx & 127;
      int grow;
      if (role == 0)      grow = (r >> 4) * H_ + sub * 16 + (r & 15);
      else if (role == 1) grow = sub * 16 + r;
      else                grow = sub * 48 + r;
      s8v v = *reinterpret_cast<const s8v*>(src + (size_t)grow * 1024 + c * 8);
      unsigned o = (unsigned)r * 2048u + (((unsigned)(c * 16)) ^ ((unsigned)((r & 7) << 4)));
      *reinterpret_cast<s8v*>((char*)ldsW + o) = v;
    }
    __syncthreads();
  }

  const int rr = l & 15;
  const int m0 = w * 16;
  const int rb = (l >> 4) * 4, c15 = l & 15;

  for (int t = 0; t < TS_; t++) {
    ushort* h1t  = p.h1b  + (size_t)t * B_ * H_;
    ushort* hidt = p.hidb + (size_t)t * B_ * C_;
    ushort* gh1t = p.gh1b + (size_t)t * B_ * 3 * H_;
    ushort* h2t  = p.H2b  + (size_t)t * B_ * H_;

    if (role == 0) {
      // ---- phase A: h1 = GRU0(h_prev) ----
      if (t) waitflag(flg(p.flags, FD), (unsigned)t);
      const ushort* hpb = t ? (p.H2b + (size_t)(t - 1) * B_ * H_) : p.h0b;
      const ushort* gi0t = p.gi0b + (size_t)t * B_ * 3 * H_;
      int c = sub * 16 + c15;
      f4v aR = {0.f,0.f,0.f,0.f}, aZ = {0.f,0.f,0.f,0.f}, aN = {0.f,0.f,0.f,0.f};
#pragma unroll 4
      for (int kb = 0; kb < H_; kb += 32) {
        s8v a = ldfrag(hpb, H_, m0, kb, l);
        aR = __builtin_amdgcn_mfma_f32_16x16x32_bf16(a, ldsfrag(ldsW, rr, kb, l), aR, 0, 0, 0);
        aZ = __builtin_amdgcn_mfma_f32_16x16x32_bf16(a, ldsfrag(ldsW, 16 + rr, kb, l), aZ, 0, 0, 0);
        aN = __builtin_amdgcn_mfma_f32_16x16x32_bf16(a, ldsfrag(ldsW, 32 + rr, kb, l), aN, 0, 0, 0);
      }
#pragma unroll
      for (int i = 0; i < 4; i++) {
        int m = m0 + rb + i;
        const ushort* gi = gi0t + (size_t)m * (3 * H_);
        float gir = b2f(gi[c]), giz = b2f(gi[H_ + c]), gin = b2f(gi[2 * H_ + c]);
        float ghr = aR[i] + p.bhh0[c], ghz = aZ[i] + p.bhh0[H_ + c], ghn = aN[i] + p.bhh0[2 * H_ + c];
        float r = sigm(gir + ghr);
        float zg = sigm(giz + ghz);
        float nn = tanh_fast(gin + r * ghn);
        float h1 = (1.f - zg) * nn + zg * b2f(hpb[(size_t)m * H_ + c]);
        stile[m * 16 + c15] = f2b(h1);
      }
      __syncthreads();
      {
        int row = tid >> 2, ch = tid & 3;
        u64 v = *reinterpret_cast<u64*>(&stile[row * 16 + ch * 4]);
        st_sc8(&h1t[(size_t)row * H_ + sub * 16 + ch * 4], v);
      }
      arrive(flg(p.flags, FA) + sub, (unsigned)(t + 1));

    } else if (role == 1) {
      // ---- hid = h1 @ Wh2c.T (16-col slice) ----
      waitflag(flg(p.flags, FA), (unsigned)(t + 1));
      {
        f4v acc = {0.f,0.f,0.f,0.f};
#pragma unroll 4
        for (int kb = 0; kb < H_; kb += 32) {
          s8v a = ldfrag(h1t, H_, m0, kb, l);
          acc = __builtin_amdgcn_mfma_f32_16x16x32_bf16(a, ldsfrag(ldsW, rr, kb, l), acc, 0, 0, 0);
        }
#pragma unroll
        for (int i = 0; i < 4; i++) stile[(m0 + rb + i) * 16 + c15] = f2b(acc[i]);
        __syncthreads();
        int row = tid >> 2, ch = tid & 3;
        u64 v = *reinterpret_cast<u64*>(&stile[row * 16 + ch * 4]);
        st_sc8(&hidt[(size_t)row * C_ + sub * 16 + ch * 4], v);
      }
      arrive(flg(p.flags, FH) + sub, (unsigned)(t + 1));

      // ---- fused: attention + K-weighted-sum + GRU1 epilogue (b = sub) ----
      waitflag(flg(p.flags, FH), (unsigned)(t + 1));
      {
        int b = sub;
        s8v hv8 = *reinterpret_cast<const s8v*>(hidt + (size_t)b * C_ + tid * 8);
#pragma unroll
        for (int j = 0; j < 8; j++) hs[tid * 8 + j] = b2f((ushort)hv8[j]);
        __syncthreads();
        for (int s = w; s < S_; s += 4) {
          const ushort* row = p.ctxpb + ((size_t)s * B_ + b) * C_;
          float a = 0.f;
          for (int c4 = l * 4; c4 < C_; c4 += 256) {
            ushort4 cv = *reinterpret_cast<const ushort4*>(row + c4);
            f4v hv4 = *reinterpret_cast<const f4v*>(&hs[c4]);
            float4 wv = *reinterpret_cast<const float4*>(p.wmlp + c4);
            a += tanh_fast(b2f(cv.x) + hv4[0]) * wv.x;
            a += tanh_fast(b2f(cv.y) + hv4[1]) * wv.y;
            a += tanh_fast(b2f(cv.z) + hv4[2]) * wv.z;
            a += tanh_fast(b2f(cv.w) + hv4[3]) * wv.w;
          }
          for (int m = 32; m; m >>= 1) a += __shfl_xor(a, m, 64);
          if (l == 0) sc[s] = a;
        }
        __syncthreads();
        float mx = -1e30f;
        for (int s = 0; s < S_; s++) mx = fmaxf(mx, sc[s]);
        float sm = 0.f;
        for (int s = 0; s < S_; s++) sm += __expf(sc[s] - mx);
        if (tid < S_) al[tid] = __expf(sc[tid] - mx) / sm;
        __syncthreads();

        int c0 = tid * 4;
        // gi1 = sum_s al[s] * K[b,g,s,:] — only needs al + prologue Kp => BEFORE the FG wait
        const ushort* kb0 = p.Kp + (size_t)b * 153600 + c0;   // 3*50*1024 per b
        float rc0=0.f,rc1=0.f,rc2=0.f,rc3=0.f, zc0=0.f,zc1=0.f,zc2=0.f,zc3=0.f,
              nc0=0.f,nc1=0.f,nc2=0.f,nc3=0.f;
#pragma unroll 2
        for (int s = 0; s < S_; s++) {
          float a = al[s];
          ushort4 kr = *reinterpret_cast<const ushort4*>(kb0 + s * 1024);
          ushort4 kz = *reinterpret_cast<const ushort4*>(kb0 + 51200 + s * 1024);
          ushort4 kn = *reinterpret_cast<const ushort4*>(kb0 + 102400 + s * 1024);
          rc0 += a * b2f(kr.x); rc1 += a * b2f(kr.y); rc2 += a * b2f(kr.z); rc3 += a * b2f(kr.w);
          zc0 += a * b2f(kz.x); zc1 += a * b2f(kz.y); zc2 += a * b2f(kz.z); zc3 += a * b2f(kz.w);
          nc0 += a * b2f(kn.x); nc1 += a * b2f(kn.y); nc2 += a * b2f(kn.z); nc3 += a * b2f(kn.w);
        }

        waitflag(flg(p.flags, FG), (unsigned)(t + 1));   // gh1 ready (overlapped by K-sum)

        u64 ghr8 = *reinterpret_cast<const u64*>(&gh1t[(size_t)b * 3072 + c0]);
        u64 ghz8 = *reinterpret_cast<const u64*>(&gh1t[(size_t)b * 3072 + 1024 + c0]);
        u64 ghn8 = *reinterpret_cast<const u64*>(&gh1t[(size_t)b * 3072 + 2048 + c0]);
        u64 h18  = *reinterpret_cast<const u64*>(&h1t[(size_t)b * 1024 + c0]);
        float rcv[4] = {rc0, rc1, rc2, rc3};
        float zcv[4] = {zc0, zc1, zc2, zc3};
        float ncv[4] = {nc0, nc1, nc2, nc3};
        u64 outp = 0;
#pragma unroll
        for (int j = 0; j < 4; j++) {
          int c = c0 + j;
          float gir = rcv[j] + p.bih1[c];
          float giz = zcv[j] + p.bih1[H_ + c];
          float gin = ncv[j] + p.bih1[2 * H_ + c];
          float ghr = b2f((ushort)(ghr8 >> (16 * j))) + p.bhh1[c];
          float ghz = b2f((ushort)(ghz8 >> (16 * j))) + p.bhh1[H_ + c];
          float ghn = b2f((ushort)(ghn8 >> (16 * j))) + p.bhh1[2 * H_ + c];
          float r = sigm(gir + ghr);
          float zg = sigm(giz + ghz);
          float nn = tanh_fast(gin + r * ghn);
          float h1v = b2f((ushort)(h18 >> (16 * j)));
          float h2 = (1.f - zg) * nn + zg * h1v;
          outp |= (u64)f2b(h2) << (16 * j);
        }
        st_sc8(&h2t[(size_t)b * 1024 + c0], outp);
      }
      arrive(flg(p.flags, FD) + sub, (unsigned)(t + 1));

    } else {
      // ---- gh1 = h1 @ Whh1.T (48-col slice) -> bf16 ----
      waitflag(flg(p.flags, FA), (unsigned)(t + 1));
      {
        f4v aR = {0.f,0.f,0.f,0.f}, aZ = {0.f,0.f,0.f,0.f}, aN = {0.f,0.f,0.f,0.f};
#pragma unroll 4
        for (int kb = 0; kb < H_; kb += 32) {
          s8v a = ldfrag(h1t, H_, m0, kb, l);
          aR = __builtin_amdgcn_mfma_f32_16x16x32_bf16(a, ldsfrag(ldsW, rr, kb, l), aR, 0, 0, 0);
          aZ = __builtin_amdgcn_mfma_f32_16x16x32_bf16(a, ldsfrag(ldsW, 16 + rr, kb, l), aZ, 0, 0, 0);
          aN = __builtin_amdgcn_mfma_f32_16x16x32_bf16(a, ldsfrag(ldsW, 32 + rr, kb, l), aN, 0, 0, 0);
        }
#pragma unroll
        for (int i = 0; i < 4; i++) {
          int m = m0 + rb + i;
          stile3[m * 48 + c15]      = f2b(aR[i]);
          stile3[m * 48 + 16 + c15] = f2b(aZ[i]);
          stile3[m * 48 + 32 + c15] = f2b(aN[i]);
        }
        __syncthreads();
#pragma unroll
        for (int j = 0; j < 3; j++) {
          int idx = tid + 256 * j;
          int row = idx / 12, k = idx % 12, lc4 = k * 4;
          u64 v = *reinterpret_cast<u64*>(&stile3[row * 48 + lc4]);
          st_sc8(&gh1t[(size_t)row * (3 * H_) + (lc4 >> 4) * H_ + sub * 16 + (lc4 & 15)], v);
        }
      }
      arrive(flg(p.flags, FG) + sub, (unsigned)(t + 1));
    }
  }
}

// ---------------- epilogue: streaming LSE over vocab, fp8 x4 row-tiles ----------------
#define LSE_NCH 40
#define LSE_TILES 50    // 16-col tiles per chunk (40*50*16 = 32000)

__global__ __launch_bounds__(512) void k_lse3(const unsigned char* __restrict__ logit8,
                                              const unsigned char* __restrict__ wop8,
                                              const float* __restrict__ bop,
                                              float* __restrict__ part) {
  __shared__ __align__(16) unsigned char Bs[2][16 * 512];  // 2 x 8KB (16 rows x 512B fp8)
  int tid = threadIdx.x, l = tid & 63, w = tid >> 6;
  int r0 = blockIdx.y * 512 + w * 64;      // wave: 4 row-tiles of 16
  int c0 = blockIdx.x * 800;
  int arow_base = r0 + (l & 15);

  u64 afr[4][16];
#pragma unroll
  for (int tI = 0; tI < 4; tI++) {
    int ar = arow_base + tI * 16;
    bool ok = ar < NR_;
#pragma unroll
    for (int kk = 0; kk < 16; kk++)
      afr[tI][kk] = ok ? *reinterpret_cast<const u64*>(logit8 + (size_t)ar * 512 + kk * 32 + ((l >> 4) << 3)) : 0ull;
  }

  const int srow = tid >> 5;
  const int sc16 = (tid & 31) * 16;
  const unsigned sxr = (unsigned)((srow & 7) << 3);
  const int brow = l & 15;
  const unsigned bxr = (unsigned)((brow & 7) << 3);
  unsigned char* s0 = &Bs[0][0] + srow * 512;
  unsigned char* s1 = &Bs[1][0] + srow * 512;
  const unsigned char* rb0 = &Bs[0][0] + brow * 512;
  const unsigned char* rb1 = &Bs[1][0] + brow * 512;

  f4v mr[4], sr[4];
#pragma unroll
  for (int tI = 0; tI < 4; tI++) {
    mr[tI] = f4v{-1e30f, -1e30f, -1e30f, -1e30f};
    sr[tI] = f4v{0.f, 0.f, 0.f, 0.f};
  }

  {
    const unsigned char* src = wop8 + (size_t)(c0 + srow) * 512 + sc16;
    u64 g0 = *reinterpret_cast<const u64*>(src);
    u64 g1 = *reinterpret_cast<const u64*>(src + 8);
    *reinterpret_cast<u64*>(s0 + (((unsigned)sc16) ^ sxr)) = g0;
    *reinterpret_cast<u64*>(s0 + (((unsigned)sc16 + 8u) ^ sxr)) = g1;
  }
  __syncthreads();

  for (int tt = 0; tt < LSE_TILES; tt++) {
    int cur = tt & 1;
    bool more = (tt + 1) < LSE_TILES;
    u64 g0, g1;
    if (more) {
      const unsigned char* src = wop8 + (size_t)(c0 + (tt + 1) * 16 + srow) * 512 + sc16;
      g0 = *reinterpret_cast<const u64*>(src);
      g1 = *reinterpret_cast<const u64*>(src + 8);
    }
    const unsigned char* rb = cur ? rb1 : rb0;
    f4v acc[4] = {{0.f,0.f,0.f,0.f},{0.f,0.f,0.f,0.f},{0.f,0.f,0.f,0.f},{0.f,0.f,0.f,0.f}};
#pragma unroll
    for (int kk = 0; kk < 16; kk++) {
      u64 b = *reinterpret_cast<const u64*>(rb + ((unsigned)(kk * 32 + ((l >> 4) << 3)) ^ bxr));
#pragma unroll
      for (int tI = 0; tI < 4; tI++)
        acc[tI] = __builtin_amdgcn_mfma_f32_16x16x32_fp8_fp8((long)afr[tI][kk], (long)b, acc[tI], 0, 0, 0);
    }
    float bv = bop[c0 + tt * 16 + (l & 15)];
#pragma unroll
    for (int tI = 0; tI < 4; tI++)
#pragma unroll
      for (int i = 0; i < 4; i++) {
        float v = acc[tI][i] * 0.0625f + bv;
        if (v <= mr[tI][i]) {
          sr[tI][i] += __expf(v - mr[tI][i]);
        } else {
          sr[tI][i] = sr[tI][i] * __expf(mr[tI][i] - v) + 1.f;
          mr[tI][i] = v;
        }
      }
    if (more) {
      unsigned char* sd = cur ? s0 : s1;
      *reinterpret_cast<u64*>(sd + (((unsigned)sc16) ^ sxr)) = g0;
      *reinterpret_cast<u64*>(sd + (((unsigned)sc16 + 8u) ^ sxr)) = g1;
      __syncthreads();
    }
  }

  for (int sh = 1; sh < 16; sh <<= 1) {
#pragma unroll
    for (int tI = 0; tI < 4; tI++)
#pragma unroll
      for (int i = 0; i < 4; i++) {
        float om = __shfl_xor(mr[tI][i], sh, 64);
        float os = __shfl_xor(sr[tI][i], sh, 64);
        float mn = fmaxf(mr[tI][i], om);
        sr[tI][i] = sr[tI][i] * __expf(mr[tI][i] - mn) + os * __expf(om - mn);
        mr[tI][i] = mn;
      }
  }
  if ((l & 15) == 0) {
#pragma unroll
    for (int tI = 0; tI < 4; tI++)
#pragma unroll
      for (int i = 0; i < 4; i++) {
        int row = r0 + tI * 16 + (l >> 4) * 4 + i;
        if (row < NR_) {
          size_t o = ((size_t)row * LSE_NCH + blockIdx.x) * 2;
          part[o] = mr[tI][i];
          part[o + 1] = sr[tI][i];
        }
      }
  }
}

__global__ void k_final(const float* __restrict__ part, const ushort* __restrict__ logitb,
                        const float* __restrict__ Wop, const float* __restrict__ bop,
                        const int* __restrict__ y, float* __restrict__ nll) {
  int i = blockIdx.x * 256 + threadIdx.x;
  if (i >= NR_) return;
  float m = -1e30f;
  for (int c = 0; c < LSE_NCH; c++) m = fmaxf(m, part[((size_t)i * LSE_NCH + c) * 2]);
  float s = 0.f;
  for (int c = 0; c < LSE_NCH; c++) {
    size_t o = ((size_t)i * LSE_NCH + c) * 2;
    s += part[o + 1] * __expf(part[o] - m);
  }
  float lse = m + logf(s);
  int tgt = y[i + B_];
  float v = 0.f;
  if (tgt != 0) {
    const ushort* lr = logitb + (size_t)i * E_;
    const float* wr = Wop + (size_t)tgt * E_;
    float dot = 0.f;
    for (int k = 0; k < E_; k += 4) {
      ushort4 lv = *reinterpret_cast<const ushort4*>(lr + k);
      float4 wv = *reinterpret_cast<const float4*>(wr + k);
      dot += b2f(lv.x) * wv.x + b2f(lv.y) * wv.y + b2f(lv.z) * wv.z + b2f(lv.w) * wv.w;
    }
    dot += bop[tgt];
    v = lse - dot;
  }
  nll[i] = v;
}

__global__ void k_reduce(const float* __restrict__ nll, float* __restrict__ out) {
  __shared__ float sh[256];
  float a = 0.f;
  for (int i = threadIdx.x; i < NR_; i += 256) a += nll[i];
  sh[threadIdx.x] = a;
  __syncthreads();
  for (int s = 128; s; s >>= 1) {
    if (threadIdx.x < s) sh[threadIdx.x] += sh[threadIdx.x + s];
    __syncthreads();
  }
  if (threadIdx.x == 0) out[0] = sh[0];
}

// ---------------- host ----------------

extern "C" void kernel_launch(void* const* d_in, const int* in_sizes, int n_in,
                              void* d_out, int out_size, void* d_ws, size_t ws_size,
                              hipStream_t stream) {
  const float* ctx  = (const float*)d_in[0];
  const int*   y    = (const int*)d_in[1];
  const float* emb  = (const float*)d_in[2];
  const float* Wih0 = (const float*)d_in[3];
  const float* Whh0 = (const float*)d_in[4];
  const float* bih0 = (const float*)d_in[5];
  const float* bhh0 = (const float*)d_in[6];
  const float* Wih1 = (const float*)d_in[7];
  const float* Whh1 = (const float*)d_in[8];
  const float* bih1 = (const float*)d_in[9];
  const float* bhh1 = (const float*)d_in[10];
  const float* Wc2c = (const float*)d_in[11];
  const float* Wh2c = (const float*)d_in[12];
  const float* wmlp = (const float*)d_in[13];
  const float* Wc2h = (const float*)d_in[14];
  const float* Who  = (const float*)d_in[15];
  const float* bho  = (const float*)d_in[16];
  const float* Wop  = (const float*)d_in[17];
  const float* bop  = (const float*)d_in[18];

  char* ws = (char*)d_ws;
  size_t off = 0;
  auto alloc = [&](size_t bytes) { void* p = ws + off; off += (bytes + 4095) & ~size_t(4095); return p; };

  ushort* ctxb   = (ushort*)alloc((size_t)S_ * B_ * C_ * 2);
  ushort* wih0b  = (ushort*)alloc((size_t)3 * H_ * E_ * 2);
  ushort* whh0b  = (ushort*)alloc((size_t)3 * H_ * H_ * 2);
  ushort* wh2cb  = (ushort*)alloc((size_t)C_ * H_ * 2);
  ushort* wc2hT  = (ushort*)alloc((size_t)C_ * H_ * 2);
  ushort* wih1b  = (ushort*)alloc((size_t)3 * H_ * H_ * 2);
  ushort* whh1b  = (ushort*)alloc((size_t)3 * H_ * H_ * 2);
  ushort* whob   = (ushort*)alloc((size_t)E_ * H_ * 2);
  unsigned char* wop8 = (unsigned char*)alloc((size_t)V_ * E_);
  ushort* wc2cb  = (ushort*)alloc((size_t)C_ * C_ * 2);
  ushort* wcombb = (ushort*)alloc((size_t)3 * H_ * C_ * 2);
  ushort* Kp     = (ushort*)alloc((size_t)S_ * B_ * 3 * H_ * 2);
  ushort* xb     = (ushort*)alloc((size_t)NR_ * E_ * 2);
  ushort* gi0b   = (ushort*)alloc((size_t)NR_ * 3 * H_ * 2);
  ushort* ctxpb  = (ushort*)alloc((size_t)S_ * B_ * C_ * 2);
  ushort* H2b    = (ushort*)alloc((size_t)TS_ * B_ * H_ * 2);
  ushort* h0b    = (ushort*)alloc((size_t)B_ * H_ * 2);
  ushort* h1b    = (ushort*)alloc((size_t)TS_ * B_ * H_ * 2);
  ushort* hidb   = (ushort*)alloc((size_t)TS_ * B_ * C_ * 2);
  ushort* gh1b   = (ushort*)alloc((size_t)TS_ * B_ * 3 * H_ * 2);
  ushort* logitb = (ushort*)alloc((size_t)NR_ * E_ * 2);
  unsigned char* logit8 = (unsigned char*)alloc((size_t)NR_ * E_);
  float*  part   = (float*)alloc((size_t)2048 * LSE_NCH * 2 * 4);
  float*  nllb   = (float*)alloc((size_t)2048 * 4);
  ushort* flags  = (ushort*)alloc(4 * 128 * 2);
  (void)ws_size; (void)in_sizes; (void)n_in; (void)out_size;

  (void)hipMemsetAsync(h0b, 0, (size_t)B_ * H_ * 2, stream);
  (void)hipMemsetAsync(flags, 0, 4 * 128 * 2, stream);

  // fused prologue: 8 converts + 1 transpose + gather + wop-fp8
  PrepP pp;
  auto seg = [&](int i, const float* s, ushort* d, size_t n) {
    pp.seg[i].s = s; pp.seg[i].d = d; pp.seg[i].n4 = (unsigned)(n / 4);
  };
  seg(0, ctx, ctxb, (size_t)S_ * B_ * C_);
  seg(1, Wih0, wih0b, (size_t)3 * H_ * E_);
  seg(2, Whh0, whh0b, (size_t)3 * H_ * H_);
  seg(3, Wih1, wih1b, (size_t)3 * H_ * H_);
  seg(4, Whh1, whh1b, (size_t)3 * H_ * H_);
  seg(5, Who, whob, (size_t)E_ * H_);
  seg(6, Wc2c, wc2cb, (size_t)C_ * C_);
  seg(7, Wh2c, wh2cb, (size_t)C_ * H_);
  unsigned t0 = 0;
  for (int i = 0; i < 8; i++) t0 += pp.seg[i].n4;
  pp.tot0 = t0;
  pp.tot1 = t0 + (unsigned)(H_ * C_);
  pp.tot2 = pp.tot1 + (unsigned)(NR_ * (E_ / 4));
  pp.tot3 = pp.tot2 + (unsigned)(V_ * E_ / 4);
  pp.Wc2h = Wc2h; pp.wc2hT = wc2hT;
  pp.y = y; pp.emb = emb; pp.xb = xb;
  pp.Wop = Wop; pp.wop8 = wop8;
  k_prep<<<dim3(2048), 256, 0, stream>>>(pp);

  // 3 independent GEMMs in one dispatch: gi0, ctxp, wcomb
  GMulti gm;
  gm.j[0] = { xb,    wih0b, bih0,    gi0b,   3 * H_, E_, (3 * H_) / 128, 0 };
  gm.j[1] = { ctxb,  wc2cb, nullptr, ctxpb,  C_,     C_, C_ / 128,       (unsigned)((3 * H_ / 128) * (NR_ / 64)) };
  gm.j[2] = { wih1b, wc2hT, nullptr, wcombb, C_,     H_, C_ / 128,       gm.j[1].blk0 + (unsigned)((C_ / 128) * (S_ * B_ / 64)) };
  unsigned gtot = gm.j[2].blk0 + (unsigned)((C_ / 128) * (3 * H_ / 64));
  gemm_multi<<<dim3(gtot), 256, 0, stream>>>(gm);

  // K = ctx @ W_comb.T, written in [b][gate][s][c] layout (kperm=1)
  gemm_bt<<<dim3(3 * H_ / 128, S_ * B_ / 64), 256, 0, stream>>>(ctxb, wcombb, nullptr, Kp, nullptr,
                                                                S_ * B_, 3 * H_, C_, 0, 1);

  LoopP p;
  p.whh0b = whh0b; p.gi0b = gi0b; p.wh2cb = wh2cb; p.whh1b = whh1b;
  p.Kp = Kp; p.ctxpb = ctxpb;
  p.bhh0 = bhh0; p.bih1 = bih1; p.bhh1 = bhh1; p.wmlp = wmlp;
  p.h0b = h0b;
  p.h1b = h1b; p.hidb = hidb; p.gh1b = gh1b;
  p.H2b = H2b; p.flags = flags;
  void* args[] = { (void*)&p };
  (void)hipLaunchCooperativeKernel(k_loop, dim3(NBLK_), dim3(256), args, 0, stream);

  // logit = tanh(H2 @ Who.T + bho) -> bf16 (for k_final) + fp8 x4 (for LSE)
  gemm_bt<<<dim3(E_ / 128, NR_ / 64), 256, 0, stream>>>(H2b, whob, bho, logitb, logit8,
                                                        NR_, E_, H_, 1, 0);
  k_lse3<<<dim3(LSE_NCH, 4), 512, 0, stream>>>(logit8, wop8, bop, part);
  k_final<<<dim3(8), 256, 0, stream>>>(part, logitb, Wop, bop, y, nllb);
  k_reduce<<<dim3(1), 256, 0, stream>>>(nllb, (float*)d_out);
}